// Round 14
// baseline (598.886 us; speedup 1.0000x reference)
//
#include <hip/hip_runtime.h>
#include <hip/hip_bf16.h>

#define NPTS    200000
#define MPIL    30000
#define BATCH   2
#define GRID0   256
#define PCMIN   (-51.2f)
#define VOXEL0  (0.4f)
#define NCHUNK  118                  // ceil(MPIL/256)

#define SLOT_B  ((size_t)16777216)   // bf16 activation slot: 2*256*256*64*2
#define SLOT_F  ((size_t)33554432)   // fp32 activation slot

// weight pool offsets. pfn weights (fp32) at float offsets; conv weight FRAGMENTS
// (bf16 hi+lo, MFMA-fragment-linear) at byte offsets.
#define W0F 0
#define W1F 256
#define FB1 9216
#define FB2 156672
#define FB3 304128
#define FB4 451584
#define FB5 746496
#define FB6 1336320

// ws layout (bytes)
#define WS_FLAG 0
#define WS_OCC8 64
#define WS_OCC1 (64 + 131072)
#define WS_OCC2 (64 + 262144)
// CSR arrays live in the old fv region (2313280..9993280): written+consumed before
// conv6 writes Fx over them each call.
#define WS_CNT  2313280           // [M] int
#define WS_OFF  2433280           // [M+1] int
#define WS_CUR  2553344           // [M] int
#define WS_IDX  2673344           // [N] int, ends 3473344
#define WS_LOC  3473344           // [M] int chunk-local prefix, ends 3593344
#define WS_BS   3593344           // [NCHUNK] int chunk sums, ends 3593816
#define WS_FX   393344            // final x, 16MB (written at conv6; lifetime-disjoint)

typedef __attribute__((ext_vector_type(8))) short v8s;
typedef __attribute__((ext_vector_type(4))) float f32x4;

static __device__ __forceinline__ float b2f(__hip_bfloat16 v) { return __bfloat162float(v); }
static __device__ __forceinline__ unsigned short f2bbits(float f) {
    __hip_bfloat16 h = __float2bfloat16(f);
    union { __hip_bfloat16 h; unsigned short u; } cv; cv.h = h; return cv.u;
}
static __device__ __forceinline__ float bits2f(unsigned short h) {
    union { unsigned int u; float f; } c; c.u = ((unsigned int)h) << 16; return c.f;
}
static __device__ __forceinline__ float lo2f(unsigned int u) {
    union { unsigned int u; float f; } c; c.u = u << 16; return c.f;
}
static __device__ __forceinline__ float hi2f(unsigned int u) {
    union { unsigned int u; float f; } c; c.u = u & 0xFFFF0000u; return c.f;
}
static __device__ __forceinline__ unsigned int pack2(float a, float b) {
    return (unsigned int)f2bbits(a) | ((unsigned int)f2bbits(b) << 16);
}
// split fp32 pair -> packed bf16 hi pair + bf16 lo pair (lo = residual)
static __device__ __forceinline__ void split2(float a, float b, unsigned int& hi, unsigned int& lo) {
    unsigned short ha = f2bbits(a), hb = f2bbits(b);
    hi = (unsigned int)ha | ((unsigned int)hb << 16);
    float ra = a - bits2f(ha);
    float rb = b - bits2f(hb);
    lo = (unsigned int)f2bbits(ra) | ((unsigned int)f2bbits(rb) << 16);
}

// dtype-adaptive accessors (isb=1: bf16, isb=0: fp32); index in elements
static __device__ __forceinline__ float ldf(const void* p, size_t i, int isb) {
    return isb ? b2f(((const __hip_bfloat16*)p)[i]) : ((const float*)p)[i];
}
static __device__ __forceinline__ float4 ld4(const void* p, size_t i, int isb) {
    if (isb) {
        uint2 r = *(const uint2*)((const __hip_bfloat16*)p + i);
        return make_float4(lo2f(r.x), hi2f(r.x), lo2f(r.y), hi2f(r.y));
    }
    return *(const float4*)((const float*)p + i);
}
static __device__ __forceinline__ void st4(void* p, size_t i, int isb, float4 v) {
    if (isb) {
        uint2 pk; pk.x = pack2(v.x, v.y); pk.y = pack2(v.z, v.w);
        *(uint2*)((__hip_bfloat16*)p + i) = pk;
    } else {
        *(float4*)((float*)p + i) = v;
    }
}
static __device__ __forceinline__ void* actptr(void* ob, int slot, int isb) {
    return (char*)ob + (size_t)slot * (isb ? SLOT_B : SLOT_F);
}
static __device__ __forceinline__ float* wpool(void* ob, int isb) {
    return (float*)((char*)ob + 3 * (isb ? SLOT_B : SLOT_F));
}

// ---------------- dtype probe ----------------
__global__ void probe_kernel(const unsigned short* __restrict__ g0, int* __restrict__ flag) {
    if (threadIdx.x == 0 && blockIdx.x == 0) {
        int ok = 1;
        for (int i = 0; i < 8; i++) {
            unsigned short u = g0[i];
            if (u < 0x3E00 || u >= 0x4000) ok = 0;   // bf16 of [0.5,1.0] lands in [0x3F00,0x3F80]
        }
        *flag = ok;
    }
}

// ---------------- pfn weight conversion -> fp32 pool ----------------
__global__ __launch_bounds__(256) void cvt_kernel(const void* __restrict__ src, void* ob,
                                                  int woff, int n, const int* __restrict__ flag) {
    int isb = *flag;
    int i = blockIdx.x * 256 + threadIdx.x;
    if (i < n) wpool(ob, isb)[woff + i] = ldf(src, i, isb);
}

// ---------------- conv weights -> MFMA fragment order (bf16 hi + lo) ----------------
// fragment f = (tap*(CIN/32)+kc)*(COUT/16)+nb; element (lane,i):
//   W[tap][kc*32 + (lane>>4)*8 + i][nb*16 + (lane&15)]
// Used as the MFMA *A* operand (weights stationary): lane l then holds
// A[m=ch=l&15][k=(l>>4)*8+i] = W[k][ch] -> D[ch][px] = sum_k W[k][ch] X[px][k].
__global__ __launch_bounds__(256) void wfrag_kernel(const void* __restrict__ src, void* ob,
                                                    int fb_bytes, int CIN, int COUT,
                                                    const int* __restrict__ flag)
{
    const int isb = *flag;
    const int cnt = 9 * CIN * COUT;
    int e = blockIdx.x * 256 + threadIdx.x;
    if (e >= cnt) return;
    int i = e & 7;
    int l = (e >> 3) & 63;
    int f = e >> 9;
    int nbn = COUT >> 4, kcn = CIN >> 5;
    int nb = f % nbn;
    int kc = (f / nbn) % kcn;
    int tap = f / (nbn * kcn);
    int ci = kc * 32 + (l >> 4) * 8 + i;
    int co = nb * 16 + (l & 15);
    float wv = ldf(src, (size_t)(tap * CIN + ci) * COUT + co, isb);
    unsigned short h = f2bbits(wv);
    float rem = wv - bits2f(h);
    short* wh = (short*)((char*)ob + 3 * (isb ? SLOT_B : SLOT_F) + fb_bytes);
    wh[e] = (short)h;
    wh[cnt + e] = (short)f2bbits(rem);
}

// ---------------- CSR build: histogram / 3-phase scan / fill ----------------
__global__ __launch_bounds__(256) void hist_kernel(const int* __restrict__ unq_inv,
                                                   int* __restrict__ cnt)
{
    int n = blockIdx.x * 256 + threadIdx.x;
    if (n < NPTS) atomicAdd(&cnt[unq_inv[n]], 1);
}

// phase 1: per-256-chunk local exclusive scan + chunk totals (no cross-chunk carry)
__global__ __launch_bounds__(256) void scan1_kernel(const int* __restrict__ cnt,
                                                    int* __restrict__ loc,
                                                    int* __restrict__ bs)
{
    __shared__ int s[256];
    const int tid = threadIdx.x;
    const int i = blockIdx.x * 256 + tid;
    int v = (i < MPIL) ? cnt[i] : 0;
    s[tid] = v;
    __syncthreads();
#pragma unroll
    for (int d = 1; d < 256; d <<= 1) {
        int t = (tid >= d) ? s[tid - d] : 0;
        __syncthreads();
        s[tid] += t;
        __syncthreads();
    }
    if (i < MPIL) loc[i] = s[tid] - v;
    if (tid == 255) bs[blockIdx.x] = s[255];
}

// phase 2: exclusive scan of the NCHUNK chunk totals (serial in one thread, via LDS)
__global__ __launch_bounds__(128) void scan2_kernel(int* __restrict__ bs)
{
    __shared__ int s[NCHUNK];
    const int tid = threadIdx.x;
    for (int i = tid; i < NCHUNK; i += 128) s[i] = bs[i];
    __syncthreads();
    if (tid == 0) {
        int acc = 0;
        for (int i = 0; i < NCHUNK; i++) { int t = s[i]; s[i] = acc; acc += t; }
    }
    __syncthreads();
    for (int i = tid; i < NCHUNK; i += 128) bs[i] = s[i];
}

// phase 3: combine -> off, cur
__global__ __launch_bounds__(256) void scan3_kernel(const int* __restrict__ loc,
                                                    const int* __restrict__ bs,
                                                    int* __restrict__ off,
                                                    int* __restrict__ cur)
{
    int i = blockIdx.x * 256 + threadIdx.x;
    if (i < MPIL) {
        int e = loc[i] + bs[blockIdx.x];
        off[i] = e; cur[i] = e;
    }
    if (i == 0) off[MPIL] = NPTS;
}

__global__ __launch_bounds__(256) void fill_kernel(const int* __restrict__ unq_inv,
                                                   int* __restrict__ cur,
                                                   int* __restrict__ idxarr)
{
    int n = blockIdx.x * 256 + threadIdx.x;
    if (n >= NPTS) return;
    int p = unq_inv[n];
    int s = atomicAdd(&cur[p], 1);
    idxarr[s] = n;
}

// ---------------- PFN layer 0 (no atomics: just h0 = relu(bn(x@w0))) ----------------
__global__ __launch_bounds__(256) void pfn0_kernel(
    const void* __restrict__ feat, void* ob, const void* __restrict__ g0,
    const void* __restrict__ b0, const int* __restrict__ flag)
{
    const int isb = *flag;
    int n = blockIdx.x * 256 + threadIdx.x;
    if (n >= NPTS) return;
    const float* w0f = wpool(ob, isb) + W0F;
    void* h0 = actptr(ob, 1, isb);
    float f[16];
#pragma unroll
    for (int i = 0; i < 16; i += 4) {
        float4 v = ld4(feat, (size_t)n * 16 + i, isb);
        f[i] = v.x; f[i + 1] = v.y; f[i + 2] = v.z; f[i + 3] = v.w;
    }
#pragma unroll
    for (int co = 0; co < 16; co += 4) {
        float a0 = 0.f, a1 = 0.f, a2 = 0.f, a3 = 0.f;
#pragma unroll
        for (int ci = 0; ci < 16; ci++) {
            float4 w = *(const float4*)&w0f[ci * 16 + co];
            a0 += f[ci] * w.x; a1 += f[ci] * w.y; a2 += f[ci] * w.z; a3 += f[ci] * w.w;
        }
        float o[4] = { a0, a1, a2, a3 };
#pragma unroll
        for (int k = 0; k < 4; k++) {
            float z = o[k] * ldf(g0, co + k, isb) + ldf(b0, co + k, isb);
            o[k] = fmaxf(z, 0.f);
        }
        st4(h0, (size_t)n * 16 + co, isb, make_float4(o[0], o[1], o[2], o[3]));
    }
}

// ---------------- PFN layer 1, per-pillar, FUSED hmax + scatter -> BEV img + occ ----------------
// One wave per pillar, lane = output channel. Pass 1 computes the per-pillar
// channel max of h0 in-register (h0 >= 0 post-ReLU, so 0-init is exact);
// pass 2 re-reads the (now L1-hot) points and does the W1 matvec + segment max.
// Replaces the separate hmax_kernel dispatch + hmax buffer round-trip.
template<bool BF>
static __device__ __forceinline__ void pfn1p_body(
    void* ob, const void* __restrict__ g1,
    const void* __restrict__ b1, const int* __restrict__ off,
    const int* __restrict__ idxarr, const int* __restrict__ unq,
    unsigned char* __restrict__ occ)
{
    const int lane = threadIdx.x & 63;
    const int p = (blockIdx.x << 2) + (threadIdx.x >> 6);
    if (p >= MPIL) return;
    const int isb = BF ? 1 : 0;
    const float* w1f = wpool(ob, isb) + W1F;
    const void* h0 = actptr(ob, 1, isb);
    void* img = actptr(ob, 0, isb);

    float wcol[32];
#pragma unroll
    for (int k = 0; k < 32; k++) wcol[k] = w1f[k * 64 + lane];
    const float g = ldf(g1, lane, isb);
    const float be = ldf(b1, lane, isb);

    const int s0 = off[p], s1 = off[p + 1];

    // ---- pass 1: per-pillar channel max of h0 (redundant per lane, no cross-lane) ----
    float m16[16];
#pragma unroll
    for (int k = 0; k < 16; k++) m16[k] = 0.f;
    for (int s = s0; s < s1; s++) {
        const int n = idxarr[s];
        if (BF) {
            const unsigned short* hp = (const unsigned short*)h0 + (size_t)n * 16;
            uint4 a = *(const uint4*)hp;
            uint4 c = *(const uint4*)(hp + 8);
            m16[0] = fmaxf(m16[0], lo2f(a.x)); m16[1] = fmaxf(m16[1], hi2f(a.x));
            m16[2] = fmaxf(m16[2], lo2f(a.y)); m16[3] = fmaxf(m16[3], hi2f(a.y));
            m16[4] = fmaxf(m16[4], lo2f(a.z)); m16[5] = fmaxf(m16[5], hi2f(a.z));
            m16[6] = fmaxf(m16[6], lo2f(a.w)); m16[7] = fmaxf(m16[7], hi2f(a.w));
            m16[8] = fmaxf(m16[8], lo2f(c.x)); m16[9] = fmaxf(m16[9], hi2f(c.x));
            m16[10] = fmaxf(m16[10], lo2f(c.y)); m16[11] = fmaxf(m16[11], hi2f(c.y));
            m16[12] = fmaxf(m16[12], lo2f(c.z)); m16[13] = fmaxf(m16[13], hi2f(c.z));
            m16[14] = fmaxf(m16[14], lo2f(c.w)); m16[15] = fmaxf(m16[15], hi2f(c.w));
        } else {
            const float* fp = (const float*)h0 + (size_t)n * 16;
#pragma unroll
            for (int i = 0; i < 16; i += 4) {
                float4 v = *(const float4*)(fp + i);
                m16[i] = fmaxf(m16[i], v.x); m16[i + 1] = fmaxf(m16[i + 1], v.y);
                m16[i + 2] = fmaxf(m16[i + 2], v.z); m16[i + 3] = fmaxf(m16[i + 3], v.w);
            }
        }
    }
    float base = 0.f;
#pragma unroll
    for (int k = 0; k < 16; k++) base += m16[k] * wcol[16 + k];

    // ---- pass 2: W1 matvec per point + segment max (points L1-hot from pass 1) ----
    float m = 0.f;
    for (int s = s0; s < s1; s++) {
        const int n = idxarr[s];
        float h[16];
        if (BF) {
            const unsigned short* hp = (const unsigned short*)h0 + (size_t)n * 16;
            uint4 a = *(const uint4*)hp;
            uint4 c = *(const uint4*)(hp + 8);
            h[0] = lo2f(a.x); h[1] = hi2f(a.x); h[2] = lo2f(a.y); h[3] = hi2f(a.y);
            h[4] = lo2f(a.z); h[5] = hi2f(a.z); h[6] = lo2f(a.w); h[7] = hi2f(a.w);
            h[8] = lo2f(c.x); h[9] = hi2f(c.x); h[10] = lo2f(c.y); h[11] = hi2f(c.y);
            h[12] = lo2f(c.z); h[13] = hi2f(c.z); h[14] = lo2f(c.w); h[15] = hi2f(c.w);
        } else {
            const float* fp = (const float*)h0 + (size_t)n * 16;
#pragma unroll
            for (int i = 0; i < 16; i += 4) {
                float4 v = *(const float4*)(fp + i);
                h[i] = v.x; h[i + 1] = v.y; h[i + 2] = v.z; h[i + 3] = v.w;
            }
        }
        float z = base;
#pragma unroll
        for (int k = 0; k < 16; k++) z += h[k] * wcol[k];
        z = fmaxf(z * g + be, 0.f);
        m = fmaxf(m, z);
    }

    const int bb = unq[p * 3 + 0], yy = unq[p * 3 + 1], xx = unq[p * 3 + 2];
    const size_t site = ((size_t)bb * GRID0 + yy) * GRID0 + xx;
    if (BF) ((unsigned short*)img)[site * 64 + lane] = f2bbits(m);
    else    ((float*)img)[site * 64 + lane] = m;
    if (lane == 0) occ[site] = 1;
}

__global__ __launch_bounds__(256) void pfn1p_kernel(
    void* ob, const void* __restrict__ g1,
    const void* __restrict__ b1, const int* __restrict__ off,
    const int* __restrict__ idxarr, const int* __restrict__ unq,
    unsigned char* __restrict__ occ, const int* __restrict__ flag)
{
    if (*flag) pfn1p_body<true>(ob, g1, b1, off, idxarr, unq, occ);
    else       pfn1p_body<false>(ob, g1, b1, off, idxarr, unq, occ);
}

// ---------------- 3x3 max-dilation, stride 1 ----------------
__global__ __launch_bounds__(256) void dilate1_kernel(const unsigned char* __restrict__ occ,
                                                      unsigned char* __restrict__ occ1)
{
    int idx = blockIdx.x * 256 + threadIdx.x;
    if (idx >= BATCH * GRID0 * GRID0) return;
    int b = idx / (GRID0 * GRID0);
    int r = idx % (GRID0 * GRID0);
    int y = r / GRID0, x = r % GRID0;
    unsigned char v = 0;
#pragma unroll
    for (int dy = -1; dy <= 1; dy++) {
        int yy = y + dy; if (yy < 0 || yy >= GRID0) continue;
#pragma unroll
        for (int dx = -1; dx <= 1; dx++) {
            int xx = x + dx; if (xx < 0 || xx >= GRID0) continue;
            v |= occ[((size_t)b * GRID0 + yy) * GRID0 + xx];
        }
    }
    occ1[idx] = v ? 1 : 0;
}

// ---------------- 3x3 max-dilation, stride 2 ----------------
__global__ __launch_bounds__(256) void dilate2_kernel(const unsigned char* __restrict__ occ1,
                                                      unsigned char* __restrict__ occ2)
{
    int idx = blockIdx.x * 256 + threadIdx.x;
    if (idx >= BATCH * 128 * 128) return;
    int b = idx / (128 * 128);
    int r = idx % (128 * 128);
    int y = r / 128, x = r % 128;
    unsigned char v = 0;
#pragma unroll
    for (int dy = -1; dy <= 1; dy++) {
        int yy = 2 * y + dy; if (yy < 0 || yy >= GRID0) continue;
#pragma unroll
        for (int dx = -1; dx <= 1; dx++) {
            int xx = 2 * x + dx; if (xx < 0 || xx >= GRID0) continue;
            v |= occ1[((size_t)b * GRID0 + yy) * GRID0 + xx];
        }
    }
    occ2[idx] = v ? 1 : 0;
}

// ---------------- MFMA conv: weight-stationary + batched LDS reads + LIVENESS PINS ----------------
// The asm volatile("" : "+v"(x)) pins force ALL of a pass's weight fragments (and
// LDS-read results) to be simultaneously live at one point: regalloc must materialize
// the batch, so the 12 global loads issue back-to-back with ONE drain instead of being
// sunk into a serial load->wait->use chain (VGPR=44 in R9-R13 proved the sinking).
// Unlike sched_barrier(0), this does not pin the rest of the schedule (m141 risk).
template<int CIN, int COUT, int STRIDE, bool ADD_RES, bool BF, int RT, int WC, int WP, int CSPLIT>
static __device__ __forceinline__ void conv_tile(
    short* s_a, const void* in, void* outp, const void* res, const short* wh,
    const void* gamma, const void* beta, const unsigned char* mask,
    int HIN, int WIN, int HOUT, int WOUT, int b, int oy0, int ox0, int nbB)
{
    constexpr int Y_EXT = (RT - 1) * STRIDE + 3;
    constexpr int X_EXT = 15 * STRIDE + 3;
    constexpr int TSZ = Y_EXT * X_EXT * CIN;
    constexpr int NCH8 = CIN / 8;
    constexpr int RPW = RT / WP;                 // rows per wave
    constexpr int CG = COUT / 16 / CSPLIT / WC;  // 16-ch groups per wave
    constexpr int KCN = CIN / 32;
    constexpr int KCNT = 9 * KCN;                // total K chunks
    constexpr int CP = 3;                        // chunks per pass (KCNT%3==0 always)
    constexpr int NPASS = KCNT / CP;
    constexpr int NOB = COUT / 16;

    const int tid = threadIdx.x;

    __syncthreads();   // prior subtile readers done before restage
    // ---- stage input halo tile -> LDS (bf16 hi [+ lo at +TSZ]), chunk-XOR swizzle ----
    for (int i = tid; i < Y_EXT * X_EXT * NCH8; i += 256) {
        int c8 = i % NCH8;
        int r = i / NCH8;
        int xo = r % X_EXT;
        int dy = r / X_EXT;
        int yin = oy0 * STRIDE - 1 + dy;
        int xin = ox0 * STRIDE - 1 + xo;
        bool inb = (yin >= 0 && yin < HIN && xin >= 0 && xin < WIN);
        int si = (dy * X_EXT + xo) * CIN + ((c8 ^ (xo & 7)) << 3);
        size_t gi = (((size_t)b * HIN + yin) * WIN + xin) * (size_t)CIN + c8 * 8;
        if (BF) {
            uint4 v = make_uint4(0u, 0u, 0u, 0u);
            if (inb) v = *(const uint4*)((const unsigned short*)in + gi);
            *(uint4*)&s_a[si] = v;
        } else {
            float4 va = make_float4(0.f, 0.f, 0.f, 0.f);
            float4 vb = make_float4(0.f, 0.f, 0.f, 0.f);
            if (inb) {
                va = *(const float4*)((const float*)in + gi);
                vb = *(const float4*)((const float*)in + gi + 4);
            }
            uint4 hv, lv;
            split2(va.x, va.y, hv.x, lv.x);
            split2(va.z, va.w, hv.y, lv.y);
            split2(vb.x, vb.y, hv.z, lv.z);
            split2(vb.z, vb.w, hv.w, lv.w);
            *(uint4*)&s_a[si] = hv;
            *(uint4*)&s_a[TSZ + si] = lv;
        }
    }
    __syncthreads();

    const int lane = tid & 63;
    const int w = tid >> 6;
    const int cgb = nbB + (w % WC) * CG;         // wave's first 16-ch group
    const int row0 = (w / WC) * RPW;             // wave's first row
    const int l15 = lane & 15;
    const int lhi = lane >> 4;
    const short* wl = wh + 9 * CIN * COUT;

    f32x4 acc[RPW][CG];
#pragma unroll
    for (int pt = 0; pt < RPW; pt++)
#pragma unroll
        for (int g = 0; g < CG; g++) acc[pt][g] = (f32x4){0.f, 0.f, 0.f, 0.f};

#pragma unroll 1
    for (int ps = 0; ps < NPASS; ps++) {
        const int cb0 = ps * CP;
        // weight A-fragments for this pass (global; L2/L1-hot, shared by all 4 waves)
        v8s wa[CP * CG];
        v8s wo[BF ? 1 : CP * CG];
#pragma unroll
        for (int c = 0; c < CP; c++)
#pragma unroll
            for (int g = 0; g < CG; g++) {
                const size_t f = (size_t)(cb0 + c) * NOB + cgb + g;
                wa[c * CG + g] = *(const v8s*)&wh[f * 512 + lane * 8];
                if constexpr (!BF)
                    wo[c * CG + g] = *(const v8s*)&wl[f * 512 + lane * 8];
            }
        // liveness pin: force the whole batch resident (defeats load-sinking)
#pragma unroll
        for (int q = 0; q < CP * CG; q++) asm volatile("" : "+v"(wa[q]));
        if constexpr (!BF) {
#pragma unroll
            for (int q = 0; q < CP * CG; q++) asm volatile("" : "+v"(wo[q]));
        }
        // batched LDS reads: ALL CP*RPW X-fragments of this pass in flight together
        v8s xv[CP * RPW];
        v8s xl[BF ? 1 : CP * RPW];
#pragma unroll
        for (int c = 0; c < CP; c++) {
            const int cgl = cb0 + c;
            const int tap = cgl / KCN;
            const int kc = cgl - tap * KCN;
            const int ky = tap / 3, kx = tap - ky * 3;
            const int xo = l15 * STRIDE + kx;
            const int coff = (((kc * 4 + lhi) ^ (xo & 7)) << 3);
#pragma unroll
            for (int pt = 0; pt < RPW; pt++) {
                const int ba = (((row0 + pt) * STRIDE + ky) * X_EXT + xo) * CIN + coff;
                xv[c * RPW + pt] = *(const v8s*)&s_a[ba];
                if constexpr (!BF) xl[c * RPW + pt] = *(const v8s*)&s_a[TSZ + ba];
            }
        }
#pragma unroll
        for (int q = 0; q < CP * RPW; q++) asm volatile("" : "+v"(xv[q]));
        if constexpr (!BF) {
#pragma unroll
            for (int q = 0; q < CP * RPW; q++) asm volatile("" : "+v"(xl[q]));
        }
        // MFMA burst (4 MFMAs per ds_read in bf16 mode)
#pragma unroll
        for (int c = 0; c < CP; c++)
#pragma unroll
            for (int pt = 0; pt < RPW; pt++)
#pragma unroll
                for (int g = 0; g < CG; g++) {
                    acc[pt][g] = __builtin_amdgcn_mfma_f32_16x16x32_bf16(
                        wa[c * CG + g], xv[c * RPW + pt], acc[pt][g], 0, 0, 0);
                    if constexpr (!BF) {
                        acc[pt][g] = __builtin_amdgcn_mfma_f32_16x16x32_bf16(
                            wa[c * CG + g], xl[c * RPW + pt], acc[pt][g], 0, 0, 0);
                        acc[pt][g] = __builtin_amdgcn_mfma_f32_16x16x32_bf16(
                            wo[c * CG + g], xv[c * RPW + pt], acc[pt][g], 0, 0, 0);
                    }
                }
    }

    // ---- epilogue: D row = channel (lhi*4+r), col = pixel (l15) ----
    // lane writes 4 CONSECUTIVE channels of its pixel -> packed 8B/16B stores.
#pragma unroll
    for (int g = 0; g < CG; g++) {
        const int ch = (cgb + g) * 16 + lhi * 4;
        float gm[4], bt[4];
#pragma unroll
        for (int r = 0; r < 4; r++) {
            gm[r] = ldf(gamma, ch + r, BF ? 1 : 0);
            bt[r] = ldf(beta, ch + r, BF ? 1 : 0);
        }
#pragma unroll
        for (int pt = 0; pt < RPW; pt++) {
            const int oy = oy0 + row0 + pt;
            const size_t prow = ((size_t)b * HOUT + oy) * WOUT + ox0 + l15;
            const float mk = mask[prow] ? 1.f : 0.f;
            float z[4];
#pragma unroll
            for (int r = 0; r < 4; r++)
                z[r] = (acc[pt][g][r] * gm[r] + bt[r]) * mk;
            if constexpr (ADD_RES) {
                if (BF) {
                    uint2 rr = *(const uint2*)((const unsigned short*)res + prow * COUT + ch);
                    z[0] += lo2f(rr.x); z[1] += hi2f(rr.x);
                    z[2] += lo2f(rr.y); z[3] += hi2f(rr.y);
                } else {
                    float4 rr = *(const float4*)((const float*)res + prow * COUT + ch);
                    z[0] += rr.x; z[1] += rr.y; z[2] += rr.z; z[3] += rr.w;
                }
            }
#pragma unroll
            for (int r = 0; r < 4; r++) z[r] = fmaxf(z[r], 0.f);
            if (BF) {
                uint2 pk;
                pk.x = pack2(z[0], z[1]);
                pk.y = pack2(z[2], z[3]);
                *(uint2*)((unsigned short*)outp + prow * COUT + ch) = pk;
            } else {
                *(float4*)((float*)outp + prow * COUT + ch) = make_float4(z[0], z[1], z[2], z[3]);
            }
        }
    }
}

template<int CIN, int COUT, int STRIDE, int R, int RTF, int CSPLIT, bool ADD_RES>
__global__ __launch_bounds__(256) void convmf_kernel(
    void* ob, int in_slot, int out_slot, void* out_ws, int res_slot, int fb_bytes,
    const void* __restrict__ gamma, const void* __restrict__ beta,
    const unsigned char* __restrict__ mask, const int* __restrict__ flag,
    int HIN, int WIN, int HOUT, int WOUT)
{
    constexpr int X_EXT = 15 * STRIDE + 3;
    constexpr int TSZ_B = ((R - 1) * STRIDE + 3) * X_EXT * CIN;          // bf16 tile (shorts)
    constexpr int TSZ_F2 = 2 * (((RTF - 1) * STRIDE + 3) * X_EXT * CIN); // fp32 hi+lo subtile
    constexpr int LDS_SH = (TSZ_B > TSZ_F2) ? TSZ_B : TSZ_F2;
    __shared__ __align__(16) short s_a[LDS_SH];

    // XCD-aware bijective swizzle (all conv grids are multiples of 8)
    const int nbx = gridDim.x, nby = gridDim.y;
    const int nwg = nbx * nby * (int)gridDim.z;
    int bid = blockIdx.x + nbx * (blockIdx.y + nby * blockIdx.z);
    bid = (bid & 7) * (nwg >> 3) + (bid >> 3);
    const int bx = bid % nbx;
    const int byy = (bid / nbx) % nby;
    const int bzz = bid / (nbx * nby);
    const int b = bzz / CSPLIT;
    const int coh = bzz % CSPLIT;
    const int nbB = coh * (COUT / 16 / CSPLIT);

    const int isb = *flag;
    const void* in = actptr(ob, in_slot, isb);
    void* outp = out_ws ? out_ws : actptr(ob, out_slot, isb);
    const void* res = ADD_RES ? actptr(ob, res_slot, isb) : nullptr;
    const short* wh = (const short*)((const char*)ob + 3 * (isb ? SLOT_B : SLOT_F) + fb_bytes);

    if (isb) {
        conv_tile<CIN, COUT, STRIDE, ADD_RES, true, R, 1, 4, CSPLIT>(
            s_a, in, outp, res, wh, gamma, beta, mask,
            HIN, WIN, HOUT, WOUT, b, byy * R, bx * 16, nbB);
    } else {
#pragma unroll 1
        for (int p = 0; p < R / RTF; p++)
            conv_tile<CIN, COUT, STRIDE, ADD_RES, false, RTF, 4, 1, CSPLIT>(
                s_a, in, outp, res, wh, gamma, beta, mask,
                HIN, WIN, HOUT, WOUT, b, byy * R + p * RTF, bx * 16, nbB);
    }
}

// ---------------- bilinear gather -> out ----------------
__global__ __launch_bounds__(256) void gather_kernel(
    const void* __restrict__ x, const void* __restrict__ feat,
    const int* __restrict__ unq, const int* __restrict__ unq_inv,
    void* __restrict__ out, const int* __restrict__ flag)
{
    const int isb = *flag;
    int idx = blockIdx.x * 256 + threadIdx.x;
    if (idx >= NPTS * 32) return;
    int n = idx >> 5;
    int co = (idx & 31) * 4;
    float fx = ldf(feat, (size_t)n * 16 + 0, isb);
    float fy = ldf(feat, (size_t)n * 16 + 1, isb);
    float px = ((fx - PCMIN) / VOXEL0) / 2.0f;
    float py = ((fy - PCMIN) / VOXEL0) / 2.0f;
    int bi = unq[(size_t)unq_inv[n] * 3 + 0];
    int xf = (int)floorf(px), yf = (int)floorf(py);
    int x0 = min(max(xf, 0), 127), x1 = min(max(xf + 1, 0), 127);
    int y0 = min(max(yf, 0), 127), y1 = min(max(yf + 1, 0), 127);
    float x0f = (float)x0, x1f = (float)x1, y0f = (float)y0, y1f = (float)y1;
    float wa = (x1f - px) * (y1f - py);
    float wb = (x1f - px) * (py - y0f);
    float wc = (px - x0f) * (y1f - py);
    float wd = (px - x0f) * (py - y0f);
    size_t base = (size_t)bi * 128 * 128 * 128;
    float4 Ia = ld4(x, base + ((size_t)y0 * 128 + x0) * 128 + co, isb);
    float4 Ib = ld4(x, base + ((size_t)y1 * 128 + x0) * 128 + co, isb);
    float4 Ic = ld4(x, base + ((size_t)y0 * 128 + x1) * 128 + co, isb);
    float4 Id = ld4(x, base + ((size_t)y1 * 128 + x1) * 128 + co, isb);
    float4 r;
    r.x = Ia.x * wa + Ib.x * wb + Ic.x * wc + Id.x * wd;
    r.y = Ia.y * wa + Ib.y * wb + Ic.y * wc + Id.y * wd;
    r.z = Ia.z * wa + Ib.z * wb + Ic.z * wc + Id.z * wd;
    r.w = Ia.w * wa + Ib.w * wb + Ic.w * wc + Id.w * wd;
    st4(out, (size_t)n * 128 + co, isb, r);
}

extern "C" void kernel_launch(void* const* d_in, const int* in_sizes, int n_in,
                              void* d_out, int out_size, void* d_ws, size_t ws_size,
                              hipStream_t stream)
{
    (void)in_sizes; (void)n_in; (void)out_size; (void)ws_size;
    const int* unq = (const int*)d_in[1];
    const int* unq_inv = (const int*)d_in[2];

    char* ws = (char*)d_ws;
    int* flagp = (int*)(ws + WS_FLAG);
    unsigned char* occ8 = (unsigned char*)(ws + WS_OCC8);
    unsigned char* occ1m = (unsigned char*)(ws + WS_OCC1);
    unsigned char* occ2m = (unsigned char*)(ws + WS_OCC2);
    int* cnt = (int*)(ws + WS_CNT);
    int* off = (int*)(ws + WS_OFF);
    int* cur = (int*)(ws + WS_CUR);
    int* idxarr = (int*)(ws + WS_IDX);
    int* loc = (int*)(ws + WS_LOC);
    int* bs = (int*)(ws + WS_BS);
    void* Fx = (void*)(ws + WS_FX);

    probe_kernel<<<1, 64, 0, stream>>>((const unsigned short*)d_in[5], flagp);

    // pfn weights -> fp32 pool at d_out + 3*slot
    cvt_kernel<<<1, 256, 0, stream>>>(d_in[4], d_out, W0F, 256, flagp);
    cvt_kernel<<<8, 256, 0, stream>>>(d_in[7], d_out, W1F, 2048, flagp);
    // conv weights -> MFMA fragment order (bf16 hi+lo)
    wfrag_kernel<<<144, 256, 0, stream>>>(d_in[10], d_out, FB1, 64, 64, flagp);
    wfrag_kernel<<<144, 256, 0, stream>>>(d_in[13], d_out, FB2, 64, 64, flagp);
    wfrag_kernel<<<144, 256, 0, stream>>>(d_in[16], d_out, FB3, 64, 64, flagp);
    wfrag_kernel<<<288, 256, 0, stream>>>(d_in[19], d_out, FB4, 64, 128, flagp);
    wfrag_kernel<<<576, 256, 0, stream>>>(d_in[22], d_out, FB5, 128, 128, flagp);
    wfrag_kernel<<<576, 256, 0, stream>>>(d_in[25], d_out, FB6, 128, 128, flagp);

    // img = slot0: zero 32MB covers slot0 in both modes (extra lands in not-yet-written slot1)
    hipMemsetAsync(d_out, 0, SLOT_F, stream);
    hipMemsetAsync(cnt, 0, (size_t)MPIL * 4, stream);
    hipMemsetAsync(occ8, 0, 131072, stream);

    // CSR build (hist -> 3-phase scan -> fill) + PFN (atomic-free segment max)
    hist_kernel<<<(NPTS + 255) / 256, 256, 0, stream>>>(unq_inv, cnt);
    scan1_kernel<<<NCHUNK, 256, 0, stream>>>(cnt, loc, bs);
    scan2_kernel<<<1, 128, 0, stream>>>(bs);
    scan3_kernel<<<NCHUNK, 256, 0, stream>>>(loc, bs, off, cur);
    fill_kernel<<<(NPTS + 255) / 256, 256, 0, stream>>>(unq_inv, cur, idxarr);
    pfn0_kernel<<<(NPTS + 255) / 256, 256, 0, stream>>>(d_in[0], d_out, d_in[5], d_in[6], flagp);
    pfn1p_kernel<<<(MPIL + 3) / 4, 256, 0, stream>>>(d_out, d_in[8], d_in[9],
                                                     off, idxarr, unq, occ8, flagp);

    dilate1_kernel<<<(BATCH * GRID0 * GRID0) / 256, 256, 0, stream>>>(occ8, occ1m);
    dilate2_kernel<<<(BATCH * 128 * 128) / 256, 256, 0, stream>>>(occ1m, occ2m);

    dim3 blk(256);
    // block 1 (64ch, stride 1): R=8, WC=1/WP=4 (CG=4, RPW=2), 1024 blocks
    dim3 g1(16, 32, BATCH);
    convmf_kernel<64, 64, 1, 8, 2, 1, false><<<g1, blk, 0, stream>>>(
        d_out, 0, 1, nullptr, 0, FB1, d_in[11], d_in[12], occ1m, flagp, 256, 256, 256, 256);
    convmf_kernel<64, 64, 1, 8, 2, 1, false><<<g1, blk, 0, stream>>>(
        d_out, 1, 2, nullptr, 0, FB2, d_in[14], d_in[15], occ1m, flagp, 256, 256, 256, 256);
    convmf_kernel<64, 64, 1, 8, 2, 1, true><<<g1, blk, 0, stream>>>(
        d_out, 2, 0, nullptr, 1, FB3, d_in[17], d_in[18], occ1m, flagp, 256, 256, 256, 256);
    // block 2: stride-2 (R=4) and 128ch (R=4), COUT-split x2, WC=1/WP=4 (CG=4, RPW=1)
    dim3 g2a(8, 32, BATCH * 2), g2b(8, 32, BATCH * 2);
    convmf_kernel<64, 128, 2, 4, 1, 2, false><<<g2a, blk, 0, stream>>>(
        d_out, 0, 1, nullptr, 0, FB4, d_in[20], d_in[21], occ2m, flagp, 256, 256, 128, 128);
    convmf_kernel<128, 128, 1, 4, 1, 2, false><<<g2b, blk, 0, stream>>>(
        d_out, 1, 2, nullptr, 0, FB5, d_in[23], d_in[24], occ2m, flagp, 128, 128, 128, 128);
    convmf_kernel<128, 128, 1, 4, 1, 2, true><<<g2b, blk, 0, stream>>>(
        d_out, 2, 0, Fx, 1, FB6, d_in[26], d_in[27], occ2m, flagp, 128, 128, 128, 128);

    // gather reads Fx (ws) + flag (ws), overwrites all of d_out
    gather_kernel<<<(NPTS * 32) / 256, 256, 0, stream>>>(Fx, d_in[0], unq, unq_inv,
                                                         d_out, flagp);
}

// Round 15
// 549.563 us; speedup vs baseline: 1.0898x; 1.0898x over previous
//
#include <hip/hip_runtime.h>
#include <hip/hip_bf16.h>

#define NPTS    200000
#define MPIL    30000
#define BATCH   2
#define GRID0   256
#define PCMIN   (-51.2f)
#define VOXEL0  (0.4f)
#define NCHUNK  118                  // ceil(MPIL/256)

#define SLOT_B  ((size_t)16777216)   // bf16 activation slot: 2*256*256*64*2
#define SLOT_F  ((size_t)33554432)   // fp32 activation slot

// weight pool offsets. pfn weights (fp32) at float offsets; conv weight FRAGMENTS
// (bf16 hi+lo, MFMA-fragment-linear) at byte offsets.
#define W0F 0
#define W1F 256
#define FB1 9216
#define FB2 156672
#define FB3 304128
#define FB4 451584
#define FB5 746496
#define FB6 1336320

// ws layout (bytes)
#define WS_FLAG 0
#define WS_OCC8 64
#define WS_OCC1 (64 + 131072)
#define WS_OCC2 (64 + 262144)
#define WS_HMAX 393280            // [M,16] f32
// CSR arrays live in the old fv region (2313280..9993280): written+consumed before
// conv6 writes Fx over them each call.
#define WS_CNT  2313280           // [M] int
#define WS_OFF  2433280           // [M+1] int
#define WS_CUR  2553344           // [M] int
#define WS_IDX  2673344           // [N] int, ends 3473344
#define WS_LOC  3473344           // [M] int chunk-local prefix, ends 3593344
#define WS_BS   3593344           // [NCHUNK] int chunk sums, ends 3593816
#define WS_FX   393344            // final x, 16MB (written at conv6; lifetime-disjoint)

typedef __attribute__((ext_vector_type(8))) short v8s;
typedef __attribute__((ext_vector_type(4))) float f32x4;

static __device__ __forceinline__ float b2f(__hip_bfloat16 v) { return __bfloat162float(v); }
static __device__ __forceinline__ unsigned short f2bbits(float f) {
    __hip_bfloat16 h = __float2bfloat16(f);
    union { __hip_bfloat16 h; unsigned short u; } cv; cv.h = h; return cv.u;
}
static __device__ __forceinline__ float bits2f(unsigned short h) {
    union { unsigned int u; float f; } c; c.u = ((unsigned int)h) << 16; return c.f;
}
static __device__ __forceinline__ float lo2f(unsigned int u) {
    union { unsigned int u; float f; } c; c.u = u << 16; return c.f;
}
static __device__ __forceinline__ float hi2f(unsigned int u) {
    union { unsigned int u; float f; } c; c.u = u & 0xFFFF0000u; return c.f;
}
static __device__ __forceinline__ unsigned int pack2(float a, float b) {
    return (unsigned int)f2bbits(a) | ((unsigned int)f2bbits(b) << 16);
}
// split fp32 pair -> packed bf16 hi pair + bf16 lo pair (lo = residual)
static __device__ __forceinline__ void split2(float a, float b, unsigned int& hi, unsigned int& lo) {
    unsigned short ha = f2bbits(a), hb = f2bbits(b);
    hi = (unsigned int)ha | ((unsigned int)hb << 16);
    float ra = a - bits2f(ha);
    float rb = b - bits2f(hb);
    lo = (unsigned int)f2bbits(ra) | ((unsigned int)f2bbits(rb) << 16);
}

// dtype-adaptive accessors (isb=1: bf16, isb=0: fp32); index in elements
static __device__ __forceinline__ float ldf(const void* p, size_t i, int isb) {
    return isb ? b2f(((const __hip_bfloat16*)p)[i]) : ((const float*)p)[i];
}
static __device__ __forceinline__ float4 ld4(const void* p, size_t i, int isb) {
    if (isb) {
        uint2 r = *(const uint2*)((const __hip_bfloat16*)p + i);
        return make_float4(lo2f(r.x), hi2f(r.x), lo2f(r.y), hi2f(r.y));
    }
    return *(const float4*)((const float*)p + i);
}
static __device__ __forceinline__ void st4(void* p, size_t i, int isb, float4 v) {
    if (isb) {
        uint2 pk; pk.x = pack2(v.x, v.y); pk.y = pack2(v.z, v.w);
        *(uint2*)((__hip_bfloat16*)p + i) = pk;
    } else {
        *(float4*)((float*)p + i) = v;
    }
}
static __device__ __forceinline__ void* actptr(void* ob, int slot, int isb) {
    return (char*)ob + (size_t)slot * (isb ? SLOT_B : SLOT_F);
}
static __device__ __forceinline__ float* wpool(void* ob, int isb) {
    return (float*)((char*)ob + 3 * (isb ? SLOT_B : SLOT_F));
}

// ---------------- dtype probe ----------------
__global__ void probe_kernel(const unsigned short* __restrict__ g0, int* __restrict__ flag) {
    if (threadIdx.x == 0 && blockIdx.x == 0) {
        int ok = 1;
        for (int i = 0; i < 8; i++) {
            unsigned short u = g0[i];
            if (u < 0x3E00 || u >= 0x4000) ok = 0;   // bf16 of [0.5,1.0] lands in [0x3F00,0x3F80]
        }
        *flag = ok;
    }
}

// ---------------- pfn weight conversion -> fp32 pool ----------------
__global__ __launch_bounds__(256) void cvt_kernel(const void* __restrict__ src, void* ob,
                                                  int woff, int n, const int* __restrict__ flag) {
    int isb = *flag;
    int i = blockIdx.x * 256 + threadIdx.x;
    if (i < n) wpool(ob, isb)[woff + i] = ldf(src, i, isb);
}

// ---------------- conv weights -> MFMA fragment order (bf16 hi + lo) ----------------
// fragment f = (tap*(CIN/32)+kc)*(COUT/16)+nb; element (lane,i):
//   W[tap][kc*32 + (lane>>4)*8 + i][nb*16 + (lane&15)]
// Used as the MFMA *A* operand (weights stationary): lane l then holds
// A[m=ch=l&15][k=(l>>4)*8+i] = W[k][ch] -> D[ch][px] = sum_k W[k][ch] X[px][k].
__global__ __launch_bounds__(256) void wfrag_kernel(const void* __restrict__ src, void* ob,
                                                    int fb_bytes, int CIN, int COUT,
                                                    const int* __restrict__ flag)
{
    const int isb = *flag;
    const int cnt = 9 * CIN * COUT;
    int e = blockIdx.x * 256 + threadIdx.x;
    if (e >= cnt) return;
    int i = e & 7;
    int l = (e >> 3) & 63;
    int f = e >> 9;
    int nbn = COUT >> 4, kcn = CIN >> 5;
    int nb = f % nbn;
    int kc = (f / nbn) % kcn;
    int tap = f / (nbn * kcn);
    int ci = kc * 32 + (l >> 4) * 8 + i;
    int co = nb * 16 + (l & 15);
    float wv = ldf(src, (size_t)(tap * CIN + ci) * COUT + co, isb);
    unsigned short h = f2bbits(wv);
    float rem = wv - bits2f(h);
    short* wh = (short*)((char*)ob + 3 * (isb ? SLOT_B : SLOT_F) + fb_bytes);
    wh[e] = (short)h;
    wh[cnt + e] = (short)f2bbits(rem);
}

// ---------------- CSR build: histogram / 3-phase scan / fill ----------------
__global__ __launch_bounds__(256) void hist_kernel(const int* __restrict__ unq_inv,
                                                   int* __restrict__ cnt)
{
    int n = blockIdx.x * 256 + threadIdx.x;
    if (n < NPTS) atomicAdd(&cnt[unq_inv[n]], 1);
}

// phase 1: per-256-chunk local exclusive scan + chunk totals (no cross-chunk carry)
__global__ __launch_bounds__(256) void scan1_kernel(const int* __restrict__ cnt,
                                                    int* __restrict__ loc,
                                                    int* __restrict__ bs)
{
    __shared__ int s[256];
    const int tid = threadIdx.x;
    const int i = blockIdx.x * 256 + tid;
    int v = (i < MPIL) ? cnt[i] : 0;
    s[tid] = v;
    __syncthreads();
#pragma unroll
    for (int d = 1; d < 256; d <<= 1) {
        int t = (tid >= d) ? s[tid - d] : 0;
        __syncthreads();
        s[tid] += t;
        __syncthreads();
    }
    if (i < MPIL) loc[i] = s[tid] - v;
    if (tid == 255) bs[blockIdx.x] = s[255];
}

// phase 2: exclusive scan of the NCHUNK chunk totals (serial in one thread, via LDS)
__global__ __launch_bounds__(128) void scan2_kernel(int* __restrict__ bs)
{
    __shared__ int s[NCHUNK];
    const int tid = threadIdx.x;
    for (int i = tid; i < NCHUNK; i += 128) s[i] = bs[i];
    __syncthreads();
    if (tid == 0) {
        int acc = 0;
        for (int i = 0; i < NCHUNK; i++) { int t = s[i]; s[i] = acc; acc += t; }
    }
    __syncthreads();
    for (int i = tid; i < NCHUNK; i += 128) bs[i] = s[i];
}

// phase 3: combine -> off, cur
__global__ __launch_bounds__(256) void scan3_kernel(const int* __restrict__ loc,
                                                    const int* __restrict__ bs,
                                                    int* __restrict__ off,
                                                    int* __restrict__ cur)
{
    int i = blockIdx.x * 256 + threadIdx.x;
    if (i < MPIL) {
        int e = loc[i] + bs[blockIdx.x];
        off[i] = e; cur[i] = e;
    }
    if (i == 0) off[MPIL] = NPTS;
}

__global__ __launch_bounds__(256) void fill_kernel(const int* __restrict__ unq_inv,
                                                   int* __restrict__ cur,
                                                   int* __restrict__ idxarr)
{
    int n = blockIdx.x * 256 + threadIdx.x;
    if (n >= NPTS) return;
    int p = unq_inv[n];
    int s = atomicAdd(&cur[p], 1);
    idxarr[s] = n;
}

// ---------------- PFN layer 0 (no atomics: just h0 = relu(bn(x@w0))) ----------------
__global__ __launch_bounds__(256) void pfn0_kernel(
    const void* __restrict__ feat, void* ob, const void* __restrict__ g0,
    const void* __restrict__ b0, const int* __restrict__ flag)
{
    const int isb = *flag;
    int n = blockIdx.x * 256 + threadIdx.x;
    if (n >= NPTS) return;
    const float* w0f = wpool(ob, isb) + W0F;
    void* h0 = actptr(ob, 1, isb);
    float f[16];
#pragma unroll
    for (int i = 0; i < 16; i += 4) {
        float4 v = ld4(feat, (size_t)n * 16 + i, isb);
        f[i] = v.x; f[i + 1] = v.y; f[i + 2] = v.z; f[i + 3] = v.w;
    }
#pragma unroll
    for (int co = 0; co < 16; co += 4) {
        float a0 = 0.f, a1 = 0.f, a2 = 0.f, a3 = 0.f;
#pragma unroll
        for (int ci = 0; ci < 16; ci++) {
            float4 w = *(const float4*)&w0f[ci * 16 + co];
            a0 += f[ci] * w.x; a1 += f[ci] * w.y; a2 += f[ci] * w.z; a3 += f[ci] * w.w;
        }
        float o[4] = { a0, a1, a2, a3 };
#pragma unroll
        for (int k = 0; k < 4; k++) {
            float z = o[k] * ldf(g0, co + k, isb) + ldf(b0, co + k, isb);
            o[k] = fmaxf(z, 0.f);
        }
        st4(h0, (size_t)n * 16 + co, isb, make_float4(o[0], o[1], o[2], o[3]));
    }
}

// ---------------- per-pillar max of h0 via CSR (thread = pillar x channel) ----------------
__global__ __launch_bounds__(256) void hmax_kernel(
    void* ob, const int* __restrict__ off, const int* __restrict__ idxarr,
    float* __restrict__ hmax, const int* __restrict__ flag)
{
    const int isb = *flag;
    int t = blockIdx.x * 256 + threadIdx.x;
    if (t >= MPIL * 16) return;
    int p = t >> 4, ch = t & 15;
    const void* h0 = actptr(ob, 1, isb);
    float m = 0.f;
    int s1 = off[p + 1];
    for (int s = off[p]; s < s1; s++) {
        int n = idxarr[s];
        m = fmaxf(m, ldf(h0, (size_t)n * 16 + ch, isb));
    }
    hmax[t] = m;
}

// ---------------- PFN layer 1, per-pillar, fused scatter -> BEV img + occ ----------------
template<bool BF>
static __device__ __forceinline__ void pfn1p_body(
    void* ob, const float* __restrict__ hmax, const void* __restrict__ g1,
    const void* __restrict__ b1, const int* __restrict__ off,
    const int* __restrict__ idxarr, const int* __restrict__ unq,
    unsigned char* __restrict__ occ)
{
    const int lane = threadIdx.x & 63;
    const int p = (blockIdx.x << 2) + (threadIdx.x >> 6);
    if (p >= MPIL) return;
    const int isb = BF ? 1 : 0;
    const float* w1f = wpool(ob, isb) + W1F;
    const void* h0 = actptr(ob, 1, isb);
    void* img = actptr(ob, 0, isb);

    float wcol[32];
#pragma unroll
    for (int k = 0; k < 32; k++) wcol[k] = w1f[k * 64 + lane];
    float base = 0.f;
#pragma unroll
    for (int k = 0; k < 16; k++) base += hmax[(size_t)p * 16 + k] * wcol[16 + k];
    const float g = ldf(g1, lane, isb);
    const float be = ldf(b1, lane, isb);

    float m = 0.f;
    const int s1 = off[p + 1];
    for (int s = off[p]; s < s1; s++) {
        const int n = idxarr[s];
        float h[16];
        if (BF) {
            const unsigned short* hp = (const unsigned short*)h0 + (size_t)n * 16;
            uint4 a = *(const uint4*)hp;
            uint4 c = *(const uint4*)(hp + 8);
            h[0] = lo2f(a.x); h[1] = hi2f(a.x); h[2] = lo2f(a.y); h[3] = hi2f(a.y);
            h[4] = lo2f(a.z); h[5] = hi2f(a.z); h[6] = lo2f(a.w); h[7] = hi2f(a.w);
            h[8] = lo2f(c.x); h[9] = hi2f(c.x); h[10] = lo2f(c.y); h[11] = hi2f(c.y);
            h[12] = lo2f(c.z); h[13] = hi2f(c.z); h[14] = lo2f(c.w); h[15] = hi2f(c.w);
        } else {
            const float* fp = (const float*)h0 + (size_t)n * 16;
#pragma unroll
            for (int i = 0; i < 16; i += 4) {
                float4 v = *(const float4*)(fp + i);
                h[i] = v.x; h[i + 1] = v.y; h[i + 2] = v.z; h[i + 3] = v.w;
            }
        }
        float z = base;
#pragma unroll
        for (int k = 0; k < 16; k++) z += h[k] * wcol[k];
        z = fmaxf(z * g + be, 0.f);
        m = fmaxf(m, z);
    }

    const int bb = unq[p * 3 + 0], yy = unq[p * 3 + 1], xx = unq[p * 3 + 2];
    const size_t site = ((size_t)bb * GRID0 + yy) * GRID0 + xx;
    if (BF) ((unsigned short*)img)[site * 64 + lane] = f2bbits(m);
    else    ((float*)img)[site * 64 + lane] = m;
    if (lane == 0) occ[site] = 1;
}

__global__ __launch_bounds__(256) void pfn1p_kernel(
    void* ob, const float* __restrict__ hmax, const void* __restrict__ g1,
    const void* __restrict__ b1, const int* __restrict__ off,
    const int* __restrict__ idxarr, const int* __restrict__ unq,
    unsigned char* __restrict__ occ, const int* __restrict__ flag)
{
    if (*flag) pfn1p_body<true>(ob, hmax, g1, b1, off, idxarr, unq, occ);
    else       pfn1p_body<false>(ob, hmax, g1, b1, off, idxarr, unq, occ);
}

// ---------------- 3x3 max-dilation, stride 1 ----------------
__global__ __launch_bounds__(256) void dilate1_kernel(const unsigned char* __restrict__ occ,
                                                      unsigned char* __restrict__ occ1)
{
    int idx = blockIdx.x * 256 + threadIdx.x;
    if (idx >= BATCH * GRID0 * GRID0) return;
    int b = idx / (GRID0 * GRID0);
    int r = idx % (GRID0 * GRID0);
    int y = r / GRID0, x = r % GRID0;
    unsigned char v = 0;
#pragma unroll
    for (int dy = -1; dy <= 1; dy++) {
        int yy = y + dy; if (yy < 0 || yy >= GRID0) continue;
#pragma unroll
        for (int dx = -1; dx <= 1; dx++) {
            int xx = x + dx; if (xx < 0 || xx >= GRID0) continue;
            v |= occ[((size_t)b * GRID0 + yy) * GRID0 + xx];
        }
    }
    occ1[idx] = v ? 1 : 0;
}

// ---------------- 3x3 max-dilation, stride 2 ----------------
__global__ __launch_bounds__(256) void dilate2_kernel(const unsigned char* __restrict__ occ1,
                                                      unsigned char* __restrict__ occ2)
{
    int idx = blockIdx.x * 256 + threadIdx.x;
    if (idx >= BATCH * 128 * 128) return;
    int b = idx / (128 * 128);
    int r = idx % (128 * 128);
    int y = r / 128, x = r % 128;
    unsigned char v = 0;
#pragma unroll
    for (int dy = -1; dy <= 1; dy++) {
        int yy = 2 * y + dy; if (yy < 0 || yy >= GRID0) continue;
#pragma unroll
        for (int dx = -1; dx <= 1; dx++) {
            int xx = 2 * x + dx; if (xx < 0 || xx >= GRID0) continue;
            v |= occ1[((size_t)b * GRID0 + yy) * GRID0 + xx];
        }
    }
    occ2[idx] = v ? 1 : 0;
}

// ---------------- MFMA conv: weight-stationary + BATCHED LDS reads ----------------
// bf16: WC=1/WP=4 -> each wave computes ALL block channels (CG=4) for its rows:
// 4 MFMAs per ds_read_b128. Per pass (CP=3 chunks) ALL CP*RPW X-fragments are
// ds_read back-to-back into registers BEFORE the MFMA burst.
// [anchor configuration: benched 544.2 (R10) / 549.1 (R13); best of 14 rounds.
//  NOT re-modified: launch_bounds(,1), reg ping-pong, liveness pins, pad layout
//  all measured slower (R11/R12/R14). hipcc pins VGPR=44 and serializes the
//  load batch regardless of source structure -- conv floor ~60us is structural.]
template<int CIN, int COUT, int STRIDE, bool ADD_RES, bool BF, int RT, int WC, int WP, int CSPLIT>
static __device__ __forceinline__ void conv_tile(
    short* s_a, const void* in, void* outp, const void* res, const short* wh,
    const void* gamma, const void* beta, const unsigned char* mask,
    int HIN, int WIN, int HOUT, int WOUT, int b, int oy0, int ox0, int nbB)
{
    constexpr int Y_EXT = (RT - 1) * STRIDE + 3;
    constexpr int X_EXT = 15 * STRIDE + 3;
    constexpr int TSZ = Y_EXT * X_EXT * CIN;
    constexpr int NCH8 = CIN / 8;
    constexpr int RPW = RT / WP;                 // rows per wave
    constexpr int CG = COUT / 16 / CSPLIT / WC;  // 16-ch groups per wave
    constexpr int KCN = CIN / 32;
    constexpr int KCNT = 9 * KCN;                // total K chunks
    constexpr int CP = 3;                        // chunks per pass (KCNT%3==0 always)
    constexpr int NPASS = KCNT / CP;
    constexpr int NOB = COUT / 16;

    const int tid = threadIdx.x;

    __syncthreads();   // prior subtile readers done before restage
    // ---- stage input halo tile -> LDS (bf16 hi [+ lo at +TSZ]), chunk-XOR swizzle ----
    for (int i = tid; i < Y_EXT * X_EXT * NCH8; i += 256) {
        int c8 = i % NCH8;
        int r = i / NCH8;
        int xo = r % X_EXT;
        int dy = r / X_EXT;
        int yin = oy0 * STRIDE - 1 + dy;
        int xin = ox0 * STRIDE - 1 + xo;
        bool inb = (yin >= 0 && yin < HIN && xin >= 0 && xin < WIN);
        int si = (dy * X_EXT + xo) * CIN + ((c8 ^ (xo & 7)) << 3);
        size_t gi = (((size_t)b * HIN + yin) * WIN + xin) * (size_t)CIN + c8 * 8;
        if (BF) {
            uint4 v = make_uint4(0u, 0u, 0u, 0u);
            if (inb) v = *(const uint4*)((const unsigned short*)in + gi);
            *(uint4*)&s_a[si] = v;
        } else {
            float4 va = make_float4(0.f, 0.f, 0.f, 0.f);
            float4 vb = make_float4(0.f, 0.f, 0.f, 0.f);
            if (inb) {
                va = *(const float4*)((const float*)in + gi);
                vb = *(const float4*)((const float*)in + gi + 4);
            }
            uint4 hv, lv;
            split2(va.x, va.y, hv.x, lv.x);
            split2(va.z, va.w, hv.y, lv.y);
            split2(vb.x, vb.y, hv.z, lv.z);
            split2(vb.z, vb.w, hv.w, lv.w);
            *(uint4*)&s_a[si] = hv;
            *(uint4*)&s_a[TSZ + si] = lv;
        }
    }
    __syncthreads();

    const int lane = tid & 63;
    const int w = tid >> 6;
    const int cgb = nbB + (w % WC) * CG;         // wave's first 16-ch group
    const int row0 = (w / WC) * RPW;             // wave's first row
    const int l15 = lane & 15;
    const int lhi = lane >> 4;
    const short* wl = wh + 9 * CIN * COUT;

    f32x4 acc[RPW][CG];
#pragma unroll
    for (int pt = 0; pt < RPW; pt++)
#pragma unroll
        for (int g = 0; g < CG; g++) acc[pt][g] = (f32x4){0.f, 0.f, 0.f, 0.f};

#pragma unroll 1
    for (int ps = 0; ps < NPASS; ps++) {
        const int cb0 = ps * CP;
        // weight A-fragments for this pass (global; L2/L1-hot, shared by all 4 waves)
        v8s wa[CP * CG];
        v8s wo[BF ? 1 : CP * CG];
#pragma unroll
        for (int c = 0; c < CP; c++)
#pragma unroll
            for (int g = 0; g < CG; g++) {
                const size_t f = (size_t)(cb0 + c) * NOB + cgb + g;
                wa[c * CG + g] = *(const v8s*)&wh[f * 512 + lane * 8];
                if constexpr (!BF)
                    wo[c * CG + g] = *(const v8s*)&wl[f * 512 + lane * 8];
            }
        // batched LDS reads: ALL CP*RPW X-fragments of this pass in flight together
        v8s xv[CP * RPW];
        v8s xl[BF ? 1 : CP * RPW];
#pragma unroll
        for (int c = 0; c < CP; c++) {
            const int cgl = cb0 + c;
            const int tap = cgl / KCN;
            const int kc = cgl - tap * KCN;
            const int ky = tap / 3, kx = tap - ky * 3;
            const int xo = l15 * STRIDE + kx;
            const int coff = (((kc * 4 + lhi) ^ (xo & 7)) << 3);
#pragma unroll
            for (int pt = 0; pt < RPW; pt++) {
                const int ba = (((row0 + pt) * STRIDE + ky) * X_EXT + xo) * CIN + coff;
                xv[c * RPW + pt] = *(const v8s*)&s_a[ba];
                if constexpr (!BF) xl[c * RPW + pt] = *(const v8s*)&s_a[TSZ + ba];
            }
        }
        // MFMA burst (4 MFMAs per ds_read in bf16 mode)
#pragma unroll
        for (int c = 0; c < CP; c++)
#pragma unroll
            for (int pt = 0; pt < RPW; pt++)
#pragma unroll
                for (int g = 0; g < CG; g++) {
                    acc[pt][g] = __builtin_amdgcn_mfma_f32_16x16x32_bf16(
                        wa[c * CG + g], xv[c * RPW + pt], acc[pt][g], 0, 0, 0);
                    if constexpr (!BF) {
                        acc[pt][g] = __builtin_amdgcn_mfma_f32_16x16x32_bf16(
                            wa[c * CG + g], xl[c * RPW + pt], acc[pt][g], 0, 0, 0);
                        acc[pt][g] = __builtin_amdgcn_mfma_f32_16x16x32_bf16(
                            wo[c * CG + g], xv[c * RPW + pt], acc[pt][g], 0, 0, 0);
                    }
                }
    }

    // ---- epilogue: D row = channel (lhi*4+r), col = pixel (l15) ----
    // lane writes 4 CONSECUTIVE channels of its pixel -> packed 8B/16B stores.
#pragma unroll
    for (int g = 0; g < CG; g++) {
        const int ch = (cgb + g) * 16 + lhi * 4;
        float gm[4], bt[4];
#pragma unroll
        for (int r = 0; r < 4; r++) {
            gm[r] = ldf(gamma, ch + r, BF ? 1 : 0);
            bt[r] = ldf(beta, ch + r, BF ? 1 : 0);
        }
#pragma unroll
        for (int pt = 0; pt < RPW; pt++) {
            const int oy = oy0 + row0 + pt;
            const size_t prow = ((size_t)b * HOUT + oy) * WOUT + ox0 + l15;
            const float mk = mask[prow] ? 1.f : 0.f;
            float z[4];
#pragma unroll
            for (int r = 0; r < 4; r++)
                z[r] = (acc[pt][g][r] * gm[r] + bt[r]) * mk;
            if constexpr (ADD_RES) {
                if (BF) {
                    uint2 rr = *(const uint2*)((const unsigned short*)res + prow * COUT + ch);
                    z[0] += lo2f(rr.x); z[1] += hi2f(rr.x);
                    z[2] += lo2f(rr.y); z[3] += hi2f(rr.y);
                } else {
                    float4 rr = *(const float4*)((const float*)res + prow * COUT + ch);
                    z[0] += rr.x; z[1] += rr.y; z[2] += rr.z; z[3] += rr.w;
                }
            }
#pragma unroll
            for (int r = 0; r < 4; r++) z[r] = fmaxf(z[r], 0.f);
            if (BF) {
                uint2 pk;
                pk.x = pack2(z[0], z[1]);
                pk.y = pack2(z[2], z[3]);
                *(uint2*)((unsigned short*)outp + prow * COUT + ch) = pk;
            } else {
                *(float4*)((float*)outp + prow * COUT + ch) = make_float4(z[0], z[1], z[2], z[3]);
            }
        }
    }
}

template<int CIN, int COUT, int STRIDE, int R, int RTF, int CSPLIT, bool ADD_RES>
__global__ __launch_bounds__(256) void convmf_kernel(
    void* ob, int in_slot, int out_slot, void* out_ws, int res_slot, int fb_bytes,
    const void* __restrict__ gamma, const void* __restrict__ beta,
    const unsigned char* __restrict__ mask, const int* __restrict__ flag,
    int HIN, int WIN, int HOUT, int WOUT)
{
    constexpr int X_EXT = 15 * STRIDE + 3;
    constexpr int TSZ_B = ((R - 1) * STRIDE + 3) * X_EXT * CIN;          // bf16 tile (shorts)
    constexpr int TSZ_F2 = 2 * (((RTF - 1) * STRIDE + 3) * X_EXT * CIN); // fp32 hi+lo subtile
    constexpr int LDS_SH = (TSZ_B > TSZ_F2) ? TSZ_B : TSZ_F2;
    __shared__ __align__(16) short s_a[LDS_SH];

    // XCD-aware bijective swizzle (all conv grids are multiples of 8)
    const int nbx = gridDim.x, nby = gridDim.y;
    const int nwg = nbx * nby * (int)gridDim.z;
    int bid = blockIdx.x + nbx * (blockIdx.y + nby * blockIdx.z);
    bid = (bid & 7) * (nwg >> 3) + (bid >> 3);
    const int bx = bid % nbx;
    const int byy = (bid / nbx) % nby;
    const int bzz = bid / (nbx * nby);
    const int b = bzz / CSPLIT;
    const int coh = bzz % CSPLIT;
    const int nbB = coh * (COUT / 16 / CSPLIT);

    const int isb = *flag;
    const void* in = actptr(ob, in_slot, isb);
    void* outp = out_ws ? out_ws : actptr(ob, out_slot, isb);
    const void* res = ADD_RES ? actptr(ob, res_slot, isb) : nullptr;
    const short* wh = (const short*)((const char*)ob + 3 * (isb ? SLOT_B : SLOT_F) + fb_bytes);

    if (isb) {
        conv_tile<CIN, COUT, STRIDE, ADD_RES, true, R, 1, 4, CSPLIT>(
            s_a, in, outp, res, wh, gamma, beta, mask,
            HIN, WIN, HOUT, WOUT, b, byy * R, bx * 16, nbB);
    } else {
#pragma unroll 1
        for (int p = 0; p < R / RTF; p++)
            conv_tile<CIN, COUT, STRIDE, ADD_RES, false, RTF, 4, 1, CSPLIT>(
                s_a, in, outp, res, wh, gamma, beta, mask,
                HIN, WIN, HOUT, WOUT, b, byy * R + p * RTF, bx * 16, nbB);
    }
}

// ---------------- bilinear gather -> out ----------------
__global__ __launch_bounds__(256) void gather_kernel(
    const void* __restrict__ x, const void* __restrict__ feat,
    const int* __restrict__ unq, const int* __restrict__ unq_inv,
    void* __restrict__ out, const int* __restrict__ flag)
{
    const int isb = *flag;
    int idx = blockIdx.x * 256 + threadIdx.x;
    if (idx >= NPTS * 32) return;
    int n = idx >> 5;
    int co = (idx & 31) * 4;
    float fx = ldf(feat, (size_t)n * 16 + 0, isb);
    float fy = ldf(feat, (size_t)n * 16 + 1, isb);
    float px = ((fx - PCMIN) / VOXEL0) / 2.0f;
    float py = ((fy - PCMIN) / VOXEL0) / 2.0f;
    int bi = unq[(size_t)unq_inv[n] * 3 + 0];
    int xf = (int)floorf(px), yf = (int)floorf(py);
    int x0 = min(max(xf, 0), 127), x1 = min(max(xf + 1, 0), 127);
    int y0 = min(max(yf, 0), 127), y1 = min(max(yf + 1, 0), 127);
    float x0f = (float)x0, x1f = (float)x1, y0f = (float)y0, y1f = (float)y1;
    float wa = (x1f - px) * (y1f - py);
    float wb = (x1f - px) * (py - y0f);
    float wc = (px - x0f) * (y1f - py);
    float wd = (px - x0f) * (py - y0f);
    size_t base = (size_t)bi * 128 * 128 * 128;
    float4 Ia = ld4(x, base + ((size_t)y0 * 128 + x0) * 128 + co, isb);
    float4 Ib = ld4(x, base + ((size_t)y1 * 128 + x0) * 128 + co, isb);
    float4 Ic = ld4(x, base + ((size_t)y0 * 128 + x1) * 128 + co, isb);
    float4 Id = ld4(x, base + ((size_t)y1 * 128 + x1) * 128 + co, isb);
    float4 r;
    r.x = Ia.x * wa + Ib.x * wb + Ic.x * wc + Id.x * wd;
    r.y = Ia.y * wa + Ib.y * wb + Ic.y * wc + Id.y * wd;
    r.z = Ia.z * wa + Ib.z * wb + Ic.z * wc + Id.z * wd;
    r.w = Ia.w * wa + Ib.w * wb + Ic.w * wc + Id.w * wd;
    st4(out, (size_t)n * 128 + co, isb, r);
}

extern "C" void kernel_launch(void* const* d_in, const int* in_sizes, int n_in,
                              void* d_out, int out_size, void* d_ws, size_t ws_size,
                              hipStream_t stream)
{
    (void)in_sizes; (void)n_in; (void)out_size; (void)ws_size;
    const int* unq = (const int*)d_in[1];
    const int* unq_inv = (const int*)d_in[2];

    char* ws = (char*)d_ws;
    int* flagp = (int*)(ws + WS_FLAG);
    unsigned char* occ8 = (unsigned char*)(ws + WS_OCC8);
    unsigned char* occ1m = (unsigned char*)(ws + WS_OCC1);
    unsigned char* occ2m = (unsigned char*)(ws + WS_OCC2);
    float* hmax = (float*)(ws + WS_HMAX);
    int* cnt = (int*)(ws + WS_CNT);
    int* off = (int*)(ws + WS_OFF);
    int* cur = (int*)(ws + WS_CUR);
    int* idxarr = (int*)(ws + WS_IDX);
    int* loc = (int*)(ws + WS_LOC);
    int* bs = (int*)(ws + WS_BS);
    void* Fx = (void*)(ws + WS_FX);

    probe_kernel<<<1, 64, 0, stream>>>((const unsigned short*)d_in[5], flagp);

    // pfn weights -> fp32 pool at d_out + 3*slot
    cvt_kernel<<<1, 256, 0, stream>>>(d_in[4], d_out, W0F, 256, flagp);
    cvt_kernel<<<8, 256, 0, stream>>>(d_in[7], d_out, W1F, 2048, flagp);
    // conv weights -> MFMA fragment order (bf16 hi+lo)
    wfrag_kernel<<<144, 256, 0, stream>>>(d_in[10], d_out, FB1, 64, 64, flagp);
    wfrag_kernel<<<144, 256, 0, stream>>>(d_in[13], d_out, FB2, 64, 64, flagp);
    wfrag_kernel<<<144, 256, 0, stream>>>(d_in[16], d_out, FB3, 64, 64, flagp);
    wfrag_kernel<<<288, 256, 0, stream>>>(d_in[19], d_out, FB4, 64, 128, flagp);
    wfrag_kernel<<<576, 256, 0, stream>>>(d_in[22], d_out, FB5, 128, 128, flagp);
    wfrag_kernel<<<576, 256, 0, stream>>>(d_in[25], d_out, FB6, 128, 128, flagp);

    // img = slot0: zero 32MB covers slot0 in both modes (extra lands in not-yet-written slot1)
    hipMemsetAsync(d_out, 0, SLOT_F, stream);
    hipMemsetAsync(cnt, 0, (size_t)MPIL * 4, stream);
    hipMemsetAsync(occ8, 0, 131072, stream);

    // CSR build (hist -> 3-phase scan -> fill) + PFN (atomic-free segment max)
    hist_kernel<<<(NPTS + 255) / 256, 256, 0, stream>>>(unq_inv, cnt);
    scan1_kernel<<<NCHUNK, 256, 0, stream>>>(cnt, loc, bs);
    scan2_kernel<<<1, 128, 0, stream>>>(bs);
    scan3_kernel<<<NCHUNK, 256, 0, stream>>>(loc, bs, off, cur);
    fill_kernel<<<(NPTS + 255) / 256, 256, 0, stream>>>(unq_inv, cur, idxarr);
    pfn0_kernel<<<(NPTS + 255) / 256, 256, 0, stream>>>(d_in[0], d_out, d_in[5], d_in[6], flagp);
    hmax_kernel<<<(MPIL * 16 + 255) / 256, 256, 0, stream>>>(d_out, off, idxarr, hmax, flagp);
    pfn1p_kernel<<<(MPIL + 3) / 4, 256, 0, stream>>>(d_out, hmax, d_in[8], d_in[9],
                                                     off, idxarr, unq, occ8, flagp);

    dilate1_kernel<<<(BATCH * GRID0 * GRID0) / 256, 256, 0, stream>>>(occ8, occ1m);
    dilate2_kernel<<<(BATCH * 128 * 128) / 256, 256, 0, stream>>>(occ1m, occ2m);

    dim3 blk(256);
    // block 1 (64ch, stride 1): R=8, WC=1/WP=4 (CG=4, RPW=2), 1024 blocks
    dim3 g1(16, 32, BATCH);
    convmf_kernel<64, 64, 1, 8, 2, 1, false><<<g1, blk, 0, stream>>>(
        d_out, 0, 1, nullptr, 0, FB1, d_in[11], d_in[12], occ1m, flagp, 256, 256, 256, 256);
    convmf_kernel<64, 64, 1, 8, 2, 1, false><<<g1, blk, 0, stream>>>(
        d_out, 1, 2, nullptr, 0, FB2, d_in[14], d_in[15], occ1m, flagp, 256, 256, 256, 256);
    convmf_kernel<64, 64, 1, 8, 2, 1, true><<<g1, blk, 0, stream>>>(
        d_out, 2, 0, nullptr, 1, FB3, d_in[17], d_in[18], occ1m, flagp, 256, 256, 256, 256);
    // block 2: stride-2 (R=4) and 128ch (R=4), COUT-split x2, WC=1/WP=4 (CG=4, RPW=1)
    dim3 g2a(8, 32, BATCH * 2), g2b(8, 32, BATCH * 2);
    convmf_kernel<64, 128, 2, 4, 1, 2, false><<<g2a, blk, 0, stream>>>(
        d_out, 0, 1, nullptr, 0, FB4, d_in[20], d_in[21], occ2m, flagp, 256, 256, 128, 128);
    convmf_kernel<128, 128, 1, 4, 1, 2, false><<<g2b, blk, 0, stream>>>(
        d_out, 1, 2, nullptr, 0, FB5, d_in[23], d_in[24], occ2m, flagp, 128, 128, 128, 128);
    convmf_kernel<128, 128, 1, 4, 1, 2, true><<<g2b, blk, 0, stream>>>(
        d_out, 2, 0, Fx, 1, FB6, d_in[26], d_in[27], occ2m, flagp, 128, 128, 128, 128);

    // gather reads Fx (ws) + flag (ws), overwrites all of d_out
    gather_kernel<<<(NPTS * 32) / 256, 256, 0, stream>>>(Fx, d_in[0], unq, unq_inv,
                                                         d_out, flagp);
}

// Round 16
// 527.556 us; speedup vs baseline: 1.1352x; 1.0417x over previous
//
#include <hip/hip_runtime.h>
#include <hip/hip_bf16.h>

#define NPTS    200000
#define MPIL    30000
#define BATCH   2
#define GRID0   256
#define PCMIN   (-51.2f)
#define VOXEL0  (0.4f)
#define NCHUNK  118                  // ceil(MPIL/256)

#define SLOT_B  ((size_t)16777216)   // bf16 activation slot: 2*256*256*64*2
#define SLOT_F  ((size_t)33554432)   // fp32 activation slot

// weight pool offsets. pfn weights (fp32) at float offsets; conv weight FRAGMENTS
// (bf16 hi+lo, MFMA-fragment-linear) at byte offsets.
#define W0F 0
#define W1F 256
#define FB1 9216
#define FB2 156672
#define FB3 304128
#define FB4 451584
#define FB5 746496
#define FB6 1336320

// ws layout (bytes)
#define WS_FLAG 0
#define WS_OCC8 64
#define WS_OCC1 (64 + 131072)
#define WS_OCC2 (64 + 262144)
#define WS_HMAX 393280            // [M,16] f32
// CSR arrays live in the old fv region (2313280..9993280): written+consumed before
// conv6 writes Fx over them each call.
#define WS_CNT  2313280           // [M] int
#define WS_OFF  2433280           // [M+1] int
#define WS_CUR  2553344           // [M] int
#define WS_IDX  2673344           // [N] int, ends 3473344
#define WS_LOC  3473344           // [M] int chunk-local prefix, ends 3593344
#define WS_BS   3593344           // [NCHUNK] int chunk sums, ends 3593816
#define WS_FX   393344            // final x, 16MB (written at conv6; lifetime-disjoint)

typedef __attribute__((ext_vector_type(8))) short v8s;
typedef __attribute__((ext_vector_type(4))) float f32x4;

static __device__ __forceinline__ float b2f(__hip_bfloat16 v) { return __bfloat162float(v); }
static __device__ __forceinline__ unsigned short f2bbits(float f) {
    __hip_bfloat16 h = __float2bfloat16(f);
    union { __hip_bfloat16 h; unsigned short u; } cv; cv.h = h; return cv.u;
}
static __device__ __forceinline__ float bits2f(unsigned short h) {
    union { unsigned int u; float f; } c; c.u = ((unsigned int)h) << 16; return c.f;
}
static __device__ __forceinline__ float lo2f(unsigned int u) {
    union { unsigned int u; float f; } c; c.u = u << 16; return c.f;
}
static __device__ __forceinline__ float hi2f(unsigned int u) {
    union { unsigned int u; float f; } c; c.u = u & 0xFFFF0000u; return c.f;
}
static __device__ __forceinline__ unsigned int pack2(float a, float b) {
    return (unsigned int)f2bbits(a) | ((unsigned int)f2bbits(b) << 16);
}
// split fp32 pair -> packed bf16 hi pair + bf16 lo pair (lo = residual)
static __device__ __forceinline__ void split2(float a, float b, unsigned int& hi, unsigned int& lo) {
    unsigned short ha = f2bbits(a), hb = f2bbits(b);
    hi = (unsigned int)ha | ((unsigned int)hb << 16);
    float ra = a - bits2f(ha);
    float rb = b - bits2f(hb);
    lo = (unsigned int)f2bbits(ra) | ((unsigned int)f2bbits(rb) << 16);
}

// dtype-adaptive accessors (isb=1: bf16, isb=0: fp32); index in elements
static __device__ __forceinline__ float ldf(const void* p, size_t i, int isb) {
    return isb ? b2f(((const __hip_bfloat16*)p)[i]) : ((const float*)p)[i];
}
static __device__ __forceinline__ float4 ld4(const void* p, size_t i, int isb) {
    if (isb) {
        uint2 r = *(const uint2*)((const __hip_bfloat16*)p + i);
        return make_float4(lo2f(r.x), hi2f(r.x), lo2f(r.y), hi2f(r.y));
    }
    return *(const float4*)((const float*)p + i);
}
static __device__ __forceinline__ void st4(void* p, size_t i, int isb, float4 v) {
    if (isb) {
        uint2 pk; pk.x = pack2(v.x, v.y); pk.y = pack2(v.z, v.w);
        *(uint2*)((__hip_bfloat16*)p + i) = pk;
    } else {
        *(float4*)((float*)p + i) = v;
    }
}
static __device__ __forceinline__ void* actptr(void* ob, int slot, int isb) {
    return (char*)ob + (size_t)slot * (isb ? SLOT_B : SLOT_F);
}
static __device__ __forceinline__ float* wpool(void* ob, int isb) {
    return (float*)((char*)ob + 3 * (isb ? SLOT_B : SLOT_F));
}

// ---------------- dtype probe ----------------
__global__ void probe_kernel(const unsigned short* __restrict__ g0, int* __restrict__ flag) {
    if (threadIdx.x == 0 && blockIdx.x == 0) {
        int ok = 1;
        for (int i = 0; i < 8; i++) {
            unsigned short u = g0[i];
            if (u < 0x3E00 || u >= 0x4000) ok = 0;   // bf16 of [0.5,1.0] lands in [0x3F00,0x3F80]
        }
        *flag = ok;
    }
}

// ---------------- FUSED weight prep: pfn cvt (blocks 0..8) + 6x wfrag (blocks 9..1880) ----
// One dispatch replaces 8: block-uniform range branch selects layer; bodies identical
// to the former cvt_kernel / wfrag_kernel.
__global__ __launch_bounds__(256) void prep_kernel(
    void* ob, const int* __restrict__ flag,
    const void* __restrict__ s4, const void* __restrict__ s7,
    const void* __restrict__ s10, const void* __restrict__ s13,
    const void* __restrict__ s16, const void* __restrict__ s19,
    const void* __restrict__ s22, const void* __restrict__ s25)
{
    const int isb = *flag;
    int bid = blockIdx.x;

    if (bid < 9) {   // pfn weight cvt -> fp32 pool
        const void* src; int woff, n, base;
        if (bid < 1) { src = s4; woff = W0F; n = 256; base = 0; }
        else         { src = s7; woff = W1F; n = 2048; base = 1; }
        int i = (bid - base) * 256 + threadIdx.x;
        if (i < n) wpool(ob, isb)[woff + i] = ldf(src, i, isb);
        return;
    }
    bid -= 9;
    // conv weights -> MFMA fragment order (bf16 hi + lo)
    const void* src; int fb_bytes, CIN, COUT, b0;
    if (bid < 144)       { src = s10; fb_bytes = FB1; CIN = 64;  COUT = 64;  b0 = 0; }
    else if (bid < 288)  { src = s13; fb_bytes = FB2; CIN = 64;  COUT = 64;  b0 = 144; }
    else if (bid < 432)  { src = s16; fb_bytes = FB3; CIN = 64;  COUT = 64;  b0 = 288; }
    else if (bid < 720)  { src = s19; fb_bytes = FB4; CIN = 64;  COUT = 128; b0 = 432; }
    else if (bid < 1296) { src = s22; fb_bytes = FB5; CIN = 128; COUT = 128; b0 = 720; }
    else                 { src = s25; fb_bytes = FB6; CIN = 128; COUT = 128; b0 = 1296; }
    const int cnt = 9 * CIN * COUT;
    int e = (bid - b0) * 256 + threadIdx.x;
    if (e >= cnt) return;
    int i = e & 7;
    int l = (e >> 3) & 63;
    int f = e >> 9;
    int nbn = COUT >> 4, kcn = CIN >> 5;
    int nb = f % nbn;
    int kc = (f / nbn) % kcn;
    int tap = f / (nbn * kcn);
    int ci = kc * 32 + (l >> 4) * 8 + i;
    int co = nb * 16 + (l & 15);
    float wv = ldf(src, (size_t)(tap * CIN + ci) * COUT + co, isb);
    unsigned short h = f2bbits(wv);
    float rem = wv - bits2f(h);
    short* wh = (short*)((char*)ob + 3 * (isb ? SLOT_B : SLOT_F) + fb_bytes);
    wh[e] = (short)h;
    wh[cnt + e] = (short)f2bbits(rem);
}

// ---------------- CSR scan (hist fused into pfn0) ----------------
// phase 1: per-256-chunk local exclusive scan + chunk totals (no cross-chunk carry)
__global__ __launch_bounds__(256) void scan1_kernel(const int* __restrict__ cnt,
                                                    int* __restrict__ loc,
                                                    int* __restrict__ bs)
{
    __shared__ int s[256];
    const int tid = threadIdx.x;
    const int i = blockIdx.x * 256 + tid;
    int v = (i < MPIL) ? cnt[i] : 0;
    s[tid] = v;
    __syncthreads();
#pragma unroll
    for (int d = 1; d < 256; d <<= 1) {
        int t = (tid >= d) ? s[tid - d] : 0;
        __syncthreads();
        s[tid] += t;
        __syncthreads();
    }
    if (i < MPIL) loc[i] = s[tid] - v;
    if (tid == 255) bs[blockIdx.x] = s[255];
}

// phase 2: exclusive scan of the NCHUNK chunk totals (serial in one thread, via LDS)
__global__ __launch_bounds__(128) void scan2_kernel(int* __restrict__ bs)
{
    __shared__ int s[NCHUNK];
    const int tid = threadIdx.x;
    for (int i = tid; i < NCHUNK; i += 128) s[i] = bs[i];
    __syncthreads();
    if (tid == 0) {
        int acc = 0;
        for (int i = 0; i < NCHUNK; i++) { int t = s[i]; s[i] = acc; acc += t; }
    }
    __syncthreads();
    for (int i = tid; i < NCHUNK; i += 128) bs[i] = s[i];
}

// phase 3: combine -> off, cur
__global__ __launch_bounds__(256) void scan3_kernel(const int* __restrict__ loc,
                                                    const int* __restrict__ bs,
                                                    int* __restrict__ off,
                                                    int* __restrict__ cur)
{
    int i = blockIdx.x * 256 + threadIdx.x;
    if (i < MPIL) {
        int e = loc[i] + bs[blockIdx.x];
        off[i] = e; cur[i] = e;
    }
    if (i == 0) off[MPIL] = NPTS;
}

__global__ __launch_bounds__(256) void fill_kernel(const int* __restrict__ unq_inv,
                                                   int* __restrict__ cur,
                                                   int* __restrict__ idxarr)
{
    int n = blockIdx.x * 256 + threadIdx.x;
    if (n >= NPTS) return;
    int p = unq_inv[n];
    int s = atomicAdd(&cur[p], 1);
    idxarr[s] = n;
}

// ---------------- PFN layer 0 + FUSED histogram ----------------
__global__ __launch_bounds__(256) void pfn0_kernel(
    const void* __restrict__ feat, void* ob, const void* __restrict__ g0,
    const void* __restrict__ b0, const int* __restrict__ unq_inv,
    int* __restrict__ cnt, const int* __restrict__ flag)
{
    const int isb = *flag;
    int n = blockIdx.x * 256 + threadIdx.x;
    if (n >= NPTS) return;
    atomicAdd(&cnt[unq_inv[n]], 1);        // fused hist (int atomics: cheap, proven R2+)
    const float* w0f = wpool(ob, isb) + W0F;
    void* h0 = actptr(ob, 1, isb);
    float f[16];
#pragma unroll
    for (int i = 0; i < 16; i += 4) {
        float4 v = ld4(feat, (size_t)n * 16 + i, isb);
        f[i] = v.x; f[i + 1] = v.y; f[i + 2] = v.z; f[i + 3] = v.w;
    }
#pragma unroll
    for (int co = 0; co < 16; co += 4) {
        float a0 = 0.f, a1 = 0.f, a2 = 0.f, a3 = 0.f;
#pragma unroll
        for (int ci = 0; ci < 16; ci++) {
            float4 w = *(const float4*)&w0f[ci * 16 + co];
            a0 += f[ci] * w.x; a1 += f[ci] * w.y; a2 += f[ci] * w.z; a3 += f[ci] * w.w;
        }
        float o[4] = { a0, a1, a2, a3 };
#pragma unroll
        for (int k = 0; k < 4; k++) {
            float z = o[k] * ldf(g0, co + k, isb) + ldf(b0, co + k, isb);
            o[k] = fmaxf(z, 0.f);
        }
        st4(h0, (size_t)n * 16 + co, isb, make_float4(o[0], o[1], o[2], o[3]));
    }
}

// ---------------- per-pillar max of h0 via CSR (thread = pillar x channel) ----------------
__global__ __launch_bounds__(256) void hmax_kernel(
    void* ob, const int* __restrict__ off, const int* __restrict__ idxarr,
    float* __restrict__ hmax, const int* __restrict__ flag)
{
    const int isb = *flag;
    int t = blockIdx.x * 256 + threadIdx.x;
    if (t >= MPIL * 16) return;
    int p = t >> 4, ch = t & 15;
    const void* h0 = actptr(ob, 1, isb);
    float m = 0.f;
    int s1 = off[p + 1];
    for (int s = off[p]; s < s1; s++) {
        int n = idxarr[s];
        m = fmaxf(m, ldf(h0, (size_t)n * 16 + ch, isb));
    }
    hmax[t] = m;
}

// ---------------- PFN layer 1, per-pillar, fused scatter -> BEV img + occ ----------------
template<bool BF>
static __device__ __forceinline__ void pfn1p_body(
    void* ob, const float* __restrict__ hmax, const void* __restrict__ g1,
    const void* __restrict__ b1, const int* __restrict__ off,
    const int* __restrict__ idxarr, const int* __restrict__ unq,
    unsigned char* __restrict__ occ)
{
    const int lane = threadIdx.x & 63;
    const int p = (blockIdx.x << 2) + (threadIdx.x >> 6);
    if (p >= MPIL) return;
    const int isb = BF ? 1 : 0;
    const float* w1f = wpool(ob, isb) + W1F;
    const void* h0 = actptr(ob, 1, isb);
    void* img = actptr(ob, 0, isb);

    float wcol[32];
#pragma unroll
    for (int k = 0; k < 32; k++) wcol[k] = w1f[k * 64 + lane];
    float base = 0.f;
#pragma unroll
    for (int k = 0; k < 16; k++) base += hmax[(size_t)p * 16 + k] * wcol[16 + k];
    const float g = ldf(g1, lane, isb);
    const float be = ldf(b1, lane, isb);

    float m = 0.f;
    const int s1 = off[p + 1];
    for (int s = off[p]; s < s1; s++) {
        const int n = idxarr[s];
        float h[16];
        if (BF) {
            const unsigned short* hp = (const unsigned short*)h0 + (size_t)n * 16;
            uint4 a = *(const uint4*)hp;
            uint4 c = *(const uint4*)(hp + 8);
            h[0] = lo2f(a.x); h[1] = hi2f(a.x); h[2] = lo2f(a.y); h[3] = hi2f(a.y);
            h[4] = lo2f(a.z); h[5] = hi2f(a.z); h[6] = lo2f(a.w); h[7] = hi2f(a.w);
            h[8] = lo2f(c.x); h[9] = hi2f(c.x); h[10] = lo2f(c.y); h[11] = hi2f(c.y);
            h[12] = lo2f(c.z); h[13] = hi2f(c.z); h[14] = lo2f(c.w); h[15] = hi2f(c.w);
        } else {
            const float* fp = (const float*)h0 + (size_t)n * 16;
#pragma unroll
            for (int i = 0; i < 16; i += 4) {
                float4 v = *(const float4*)(fp + i);
                h[i] = v.x; h[i + 1] = v.y; h[i + 2] = v.z; h[i + 3] = v.w;
            }
        }
        float z = base;
#pragma unroll
        for (int k = 0; k < 16; k++) z += h[k] * wcol[k];
        z = fmaxf(z * g + be, 0.f);
        m = fmaxf(m, z);
    }

    const int bb = unq[p * 3 + 0], yy = unq[p * 3 + 1], xx = unq[p * 3 + 2];
    const size_t site = ((size_t)bb * GRID0 + yy) * GRID0 + xx;
    if (BF) ((unsigned short*)img)[site * 64 + lane] = f2bbits(m);
    else    ((float*)img)[site * 64 + lane] = m;
    if (lane == 0) occ[site] = 1;
}

__global__ __launch_bounds__(256) void pfn1p_kernel(
    void* ob, const float* __restrict__ hmax, const void* __restrict__ g1,
    const void* __restrict__ b1, const int* __restrict__ off,
    const int* __restrict__ idxarr, const int* __restrict__ unq,
    unsigned char* __restrict__ occ, const int* __restrict__ flag)
{
    if (*flag) pfn1p_body<true>(ob, hmax, g1, b1, off, idxarr, unq, occ);
    else       pfn1p_body<false>(ob, hmax, g1, b1, off, idxarr, unq, occ);
}

// ---------------- 3x3 max-dilation, stride 1 ----------------
__global__ __launch_bounds__(256) void dilate1_kernel(const unsigned char* __restrict__ occ,
                                                      unsigned char* __restrict__ occ1)
{
    int idx = blockIdx.x * 256 + threadIdx.x;
    if (idx >= BATCH * GRID0 * GRID0) return;
    int b = idx / (GRID0 * GRID0);
    int r = idx % (GRID0 * GRID0);
    int y = r / GRID0, x = r % GRID0;
    unsigned char v = 0;
#pragma unroll
    for (int dy = -1; dy <= 1; dy++) {
        int yy = y + dy; if (yy < 0 || yy >= GRID0) continue;
#pragma unroll
        for (int dx = -1; dx <= 1; dx++) {
            int xx = x + dx; if (xx < 0 || xx >= GRID0) continue;
            v |= occ[((size_t)b * GRID0 + yy) * GRID0 + xx];
        }
    }
    occ1[idx] = v ? 1 : 0;
}

// ---------------- 3x3 max-dilation, stride 2 ----------------
__global__ __launch_bounds__(256) void dilate2_kernel(const unsigned char* __restrict__ occ1,
                                                      unsigned char* __restrict__ occ2)
{
    int idx = blockIdx.x * 256 + threadIdx.x;
    if (idx >= BATCH * 128 * 128) return;
    int b = idx / (128 * 128);
    int r = idx % (128 * 128);
    int y = r / 128, x = r % 128;
    unsigned char v = 0;
#pragma unroll
    for (int dy = -1; dy <= 1; dy++) {
        int yy = 2 * y + dy; if (yy < 0 || yy >= GRID0) continue;
#pragma unroll
        for (int dx = -1; dx <= 1; dx++) {
            int xx = 2 * x + dx; if (xx < 0 || xx >= GRID0) continue;
            v |= occ1[((size_t)b * GRID0 + yy) * GRID0 + xx];
        }
    }
    occ2[idx] = v ? 1 : 0;
}

// ---------------- MFMA conv: weight-stationary + BATCHED LDS reads ----------------
// [anchor configuration: benched 544.2-549.6 across R10/R13/R15; best of session.
//  Conv floor ~60us is structural under hipcc (VGPR pinned 44, load batch serialized
//  regardless of source form -- launch_bounds(,1)/ping-pong/pins/pad all slower).]
template<int CIN, int COUT, int STRIDE, bool ADD_RES, bool BF, int RT, int WC, int WP, int CSPLIT>
static __device__ __forceinline__ void conv_tile(
    short* s_a, const void* in, void* outp, const void* res, const short* wh,
    const void* gamma, const void* beta, const unsigned char* mask,
    int HIN, int WIN, int HOUT, int WOUT, int b, int oy0, int ox0, int nbB)
{
    constexpr int Y_EXT = (RT - 1) * STRIDE + 3;
    constexpr int X_EXT = 15 * STRIDE + 3;
    constexpr int TSZ = Y_EXT * X_EXT * CIN;
    constexpr int NCH8 = CIN / 8;
    constexpr int RPW = RT / WP;                 // rows per wave
    constexpr int CG = COUT / 16 / CSPLIT / WC;  // 16-ch groups per wave
    constexpr int KCN = CIN / 32;
    constexpr int KCNT = 9 * KCN;                // total K chunks
    constexpr int CP = 3;                        // chunks per pass (KCNT%3==0 always)
    constexpr int NPASS = KCNT / CP;
    constexpr int NOB = COUT / 16;

    const int tid = threadIdx.x;

    __syncthreads();   // prior subtile readers done before restage
    // ---- stage input halo tile -> LDS (bf16 hi [+ lo at +TSZ]), chunk-XOR swizzle ----
    for (int i = tid; i < Y_EXT * X_EXT * NCH8; i += 256) {
        int c8 = i % NCH8;
        int r = i / NCH8;
        int xo = r % X_EXT;
        int dy = r / X_EXT;
        int yin = oy0 * STRIDE - 1 + dy;
        int xin = ox0 * STRIDE - 1 + xo;
        bool inb = (yin >= 0 && yin < HIN && xin >= 0 && xin < WIN);
        int si = (dy * X_EXT + xo) * CIN + ((c8 ^ (xo & 7)) << 3);
        size_t gi = (((size_t)b * HIN + yin) * WIN + xin) * (size_t)CIN + c8 * 8;
        if (BF) {
            uint4 v = make_uint4(0u, 0u, 0u, 0u);
            if (inb) v = *(const uint4*)((const unsigned short*)in + gi);
            *(uint4*)&s_a[si] = v;
        } else {
            float4 va = make_float4(0.f, 0.f, 0.f, 0.f);
            float4 vb = make_float4(0.f, 0.f, 0.f, 0.f);
            if (inb) {
                va = *(const float4*)((const float*)in + gi);
                vb = *(const float4*)((const float*)in + gi + 4);
            }
            uint4 hv, lv;
            split2(va.x, va.y, hv.x, lv.x);
            split2(va.z, va.w, hv.y, lv.y);
            split2(vb.x, vb.y, hv.z, lv.z);
            split2(vb.z, vb.w, hv.w, lv.w);
            *(uint4*)&s_a[si] = hv;
            *(uint4*)&s_a[TSZ + si] = lv;
        }
    }
    __syncthreads();

    const int lane = tid & 63;
    const int w = tid >> 6;
    const int cgb = nbB + (w % WC) * CG;         // wave's first 16-ch group
    const int row0 = (w / WC) * RPW;             // wave's first row
    const int l15 = lane & 15;
    const int lhi = lane >> 4;
    const short* wl = wh + 9 * CIN * COUT;

    f32x4 acc[RPW][CG];
#pragma unroll
    for (int pt = 0; pt < RPW; pt++)
#pragma unroll
        for (int g = 0; g < CG; g++) acc[pt][g] = (f32x4){0.f, 0.f, 0.f, 0.f};

#pragma unroll 1
    for (int ps = 0; ps < NPASS; ps++) {
        const int cb0 = ps * CP;
        // weight A-fragments for this pass (global; L2/L1-hot, shared by all 4 waves)
        v8s wa[CP * CG];
        v8s wo[BF ? 1 : CP * CG];
#pragma unroll
        for (int c = 0; c < CP; c++)
#pragma unroll
            for (int g = 0; g < CG; g++) {
                const size_t f = (size_t)(cb0 + c) * NOB + cgb + g;
                wa[c * CG + g] = *(const v8s*)&wh[f * 512 + lane * 8];
                if constexpr (!BF)
                    wo[c * CG + g] = *(const v8s*)&wl[f * 512 + lane * 8];
            }
        // batched LDS reads: ALL CP*RPW X-fragments of this pass in flight together
        v8s xv[CP * RPW];
        v8s xl[BF ? 1 : CP * RPW];
#pragma unroll
        for (int c = 0; c < CP; c++) {
            const int cgl = cb0 + c;
            const int tap = cgl / KCN;
            const int kc = cgl - tap * KCN;
            const int ky = tap / 3, kx = tap - ky * 3;
            const int xo = l15 * STRIDE + kx;
            const int coff = (((kc * 4 + lhi) ^ (xo & 7)) << 3);
#pragma unroll
            for (int pt = 0; pt < RPW; pt++) {
                const int ba = (((row0 + pt) * STRIDE + ky) * X_EXT + xo) * CIN + coff;
                xv[c * RPW + pt] = *(const v8s*)&s_a[ba];
                if constexpr (!BF) xl[c * RPW + pt] = *(const v8s*)&s_a[TSZ + ba];
            }
        }
        // MFMA burst (4 MFMAs per ds_read in bf16 mode)
#pragma unroll
        for (int c = 0; c < CP; c++)
#pragma unroll
            for (int pt = 0; pt < RPW; pt++)
#pragma unroll
                for (int g = 0; g < CG; g++) {
                    acc[pt][g] = __builtin_amdgcn_mfma_f32_16x16x32_bf16(
                        wa[c * CG + g], xv[c * RPW + pt], acc[pt][g], 0, 0, 0);
                    if constexpr (!BF) {
                        acc[pt][g] = __builtin_amdgcn_mfma_f32_16x16x32_bf16(
                            wa[c * CG + g], xl[c * RPW + pt], acc[pt][g], 0, 0, 0);
                        acc[pt][g] = __builtin_amdgcn_mfma_f32_16x16x32_bf16(
                            wo[c * CG + g], xv[c * RPW + pt], acc[pt][g], 0, 0, 0);
                    }
                }
    }

    // ---- epilogue: D row = channel (lhi*4+r), col = pixel (l15) ----
    // lane writes 4 CONSECUTIVE channels of its pixel -> packed 8B/16B stores.
#pragma unroll
    for (int g = 0; g < CG; g++) {
        const int ch = (cgb + g) * 16 + lhi * 4;
        float gm[4], bt[4];
#pragma unroll
        for (int r = 0; r < 4; r++) {
            gm[r] = ldf(gamma, ch + r, BF ? 1 : 0);
            bt[r] = ldf(beta, ch + r, BF ? 1 : 0);
        }
#pragma unroll
        for (int pt = 0; pt < RPW; pt++) {
            const int oy = oy0 + row0 + pt;
            const size_t prow = ((size_t)b * HOUT + oy) * WOUT + ox0 + l15;
            const float mk = mask[prow] ? 1.f : 0.f;
            float z[4];
#pragma unroll
            for (int r = 0; r < 4; r++)
                z[r] = (acc[pt][g][r] * gm[r] + bt[r]) * mk;
            if constexpr (ADD_RES) {
                if (BF) {
                    uint2 rr = *(const uint2*)((const unsigned short*)res + prow * COUT + ch);
                    z[0] += lo2f(rr.x); z[1] += hi2f(rr.x);
                    z[2] += lo2f(rr.y); z[3] += hi2f(rr.y);
                } else {
                    float4 rr = *(const float4*)((const float*)res + prow * COUT + ch);
                    z[0] += rr.x; z[1] += rr.y; z[2] += rr.z; z[3] += rr.w;
                }
            }
#pragma unroll
            for (int r = 0; r < 4; r++) z[r] = fmaxf(z[r], 0.f);
            if (BF) {
                uint2 pk;
                pk.x = pack2(z[0], z[1]);
                pk.y = pack2(z[2], z[3]);
                *(uint2*)((unsigned short*)outp + prow * COUT + ch) = pk;
            } else {
                *(float4*)((float*)outp + prow * COUT + ch) = make_float4(z[0], z[1], z[2], z[3]);
            }
        }
    }
}

template<int CIN, int COUT, int STRIDE, int R, int RTF, int CSPLIT, bool ADD_RES>
__global__ __launch_bounds__(256) void convmf_kernel(
    void* ob, int in_slot, int out_slot, void* out_ws, int res_slot, int fb_bytes,
    const void* __restrict__ gamma, const void* __restrict__ beta,
    const unsigned char* __restrict__ mask, const int* __restrict__ flag,
    int HIN, int WIN, int HOUT, int WOUT)
{
    constexpr int X_EXT = 15 * STRIDE + 3;
    constexpr int TSZ_B = ((R - 1) * STRIDE + 3) * X_EXT * CIN;          // bf16 tile (shorts)
    constexpr int TSZ_F2 = 2 * (((RTF - 1) * STRIDE + 3) * X_EXT * CIN); // fp32 hi+lo subtile
    constexpr int LDS_SH = (TSZ_B > TSZ_F2) ? TSZ_B : TSZ_F2;
    __shared__ __align__(16) short s_a[LDS_SH];

    // XCD-aware bijective swizzle (all conv grids are multiples of 8)
    const int nbx = gridDim.x, nby = gridDim.y;
    const int nwg = nbx * nby * (int)gridDim.z;
    int bid = blockIdx.x + nbx * (blockIdx.y + nby * blockIdx.z);
    bid = (bid & 7) * (nwg >> 3) + (bid >> 3);
    const int bx = bid % nbx;
    const int byy = (bid / nbx) % nby;
    const int bzz = bid / (nbx * nby);
    const int b = bzz / CSPLIT;
    const int coh = bzz % CSPLIT;
    const int nbB = coh * (COUT / 16 / CSPLIT);

    const int isb = *flag;
    const void* in = actptr(ob, in_slot, isb);
    void* outp = out_ws ? out_ws : actptr(ob, out_slot, isb);
    const void* res = ADD_RES ? actptr(ob, res_slot, isb) : nullptr;
    const short* wh = (const short*)((const char*)ob + 3 * (isb ? SLOT_B : SLOT_F) + fb_bytes);

    if (isb) {
        conv_tile<CIN, COUT, STRIDE, ADD_RES, true, R, 1, 4, CSPLIT>(
            s_a, in, outp, res, wh, gamma, beta, mask,
            HIN, WIN, HOUT, WOUT, b, byy * R, bx * 16, nbB);
    } else {
#pragma unroll 1
        for (int p = 0; p < R / RTF; p++)
            conv_tile<CIN, COUT, STRIDE, ADD_RES, false, RTF, 4, 1, CSPLIT>(
                s_a, in, outp, res, wh, gamma, beta, mask,
                HIN, WIN, HOUT, WOUT, b, byy * R + p * RTF, bx * 16, nbB);
    }
}

// ---------------- bilinear gather -> out ----------------
__global__ __launch_bounds__(256) void gather_kernel(
    const void* __restrict__ x, const void* __restrict__ feat,
    const int* __restrict__ unq, const int* __restrict__ unq_inv,
    void* __restrict__ out, const int* __restrict__ flag)
{
    const int isb = *flag;
    int idx = blockIdx.x * 256 + threadIdx.x;
    if (idx >= NPTS * 32) return;
    int n = idx >> 5;
    int co = (idx & 31) * 4;
    float fx = ldf(feat, (size_t)n * 16 + 0, isb);
    float fy = ldf(feat, (size_t)n * 16 + 1, isb);
    float px = ((fx - PCMIN) / VOXEL0) / 2.0f;
    float py = ((fy - PCMIN) / VOXEL0) / 2.0f;
    int bi = unq[(size_t)unq_inv[n] * 3 + 0];
    int xf = (int)floorf(px), yf = (int)floorf(py);
    int x0 = min(max(xf, 0), 127), x1 = min(max(xf + 1, 0), 127);
    int y0 = min(max(yf, 0), 127), y1 = min(max(yf + 1, 0), 127);
    float x0f = (float)x0, x1f = (float)x1, y0f = (float)y0, y1f = (float)y1;
    float wa = (x1f - px) * (y1f - py);
    float wb = (x1f - px) * (py - y0f);
    float wc = (px - x0f) * (y1f - py);
    float wd = (px - x0f) * (py - y0f);
    size_t base = (size_t)bi * 128 * 128 * 128;
    float4 Ia = ld4(x, base + ((size_t)y0 * 128 + x0) * 128 + co, isb);
    float4 Ib = ld4(x, base + ((size_t)y1 * 128 + x0) * 128 + co, isb);
    float4 Ic = ld4(x, base + ((size_t)y0 * 128 + x1) * 128 + co, isb);
    float4 Id = ld4(x, base + ((size_t)y1 * 128 + x1) * 128 + co, isb);
    float4 r;
    r.x = Ia.x * wa + Ib.x * wb + Ic.x * wc + Id.x * wd;
    r.y = Ia.y * wa + Ib.y * wb + Ic.y * wc + Id.y * wd;
    r.z = Ia.z * wa + Ib.z * wb + Ic.z * wc + Id.z * wd;
    r.w = Ia.w * wa + Ib.w * wb + Ic.w * wc + Id.w * wd;
    st4(out, (size_t)n * 128 + co, isb, r);
}

extern "C" void kernel_launch(void* const* d_in, const int* in_sizes, int n_in,
                              void* d_out, int out_size, void* d_ws, size_t ws_size,
                              hipStream_t stream)
{
    (void)in_sizes; (void)n_in; (void)out_size; (void)ws_size;
    const int* unq = (const int*)d_in[1];
    const int* unq_inv = (const int*)d_in[2];

    char* ws = (char*)d_ws;
    int* flagp = (int*)(ws + WS_FLAG);
    unsigned char* occ8 = (unsigned char*)(ws + WS_OCC8);
    unsigned char* occ1m = (unsigned char*)(ws + WS_OCC1);
    unsigned char* occ2m = (unsigned char*)(ws + WS_OCC2);
    float* hmax = (float*)(ws + WS_HMAX);
    int* cnt = (int*)(ws + WS_CNT);
    int* off = (int*)(ws + WS_OFF);
    int* cur = (int*)(ws + WS_CUR);
    int* idxarr = (int*)(ws + WS_IDX);
    int* loc = (int*)(ws + WS_LOC);
    int* bs = (int*)(ws + WS_BS);
    void* Fx = (void*)(ws + WS_FX);

    probe_kernel<<<1, 64, 0, stream>>>((const unsigned short*)d_in[5], flagp);

    // FUSED weight prep: pfn cvt + all 6 wfrag layers in ONE dispatch (was 8)
    prep_kernel<<<1881, 256, 0, stream>>>(d_out, flagp,
        d_in[4], d_in[7], d_in[10], d_in[13], d_in[16], d_in[19], d_in[22], d_in[25]);

    // img = slot0: zero 32MB covers slot0 in both modes (extra lands in not-yet-written slot1)
    hipMemsetAsync(d_out, 0, SLOT_F, stream);
    hipMemsetAsync(cnt, 0, (size_t)MPIL * 4, stream);
    hipMemsetAsync(occ8, 0, 131072, stream);

    // PFN layer 0 (+fused histogram) -> CSR scan -> fill -> hmax -> pfn1p
    pfn0_kernel<<<(NPTS + 255) / 256, 256, 0, stream>>>(d_in[0], d_out, d_in[5], d_in[6],
                                                        unq_inv, cnt, flagp);
    scan1_kernel<<<NCHUNK, 256, 0, stream>>>(cnt, loc, bs);
    scan2_kernel<<<1, 128, 0, stream>>>(bs);
    scan3_kernel<<<NCHUNK, 256, 0, stream>>>(loc, bs, off, cur);
    fill_kernel<<<(NPTS + 255) / 256, 256, 0, stream>>>(unq_inv, cur, idxarr);
    hmax_kernel<<<(MPIL * 16 + 255) / 256, 256, 0, stream>>>(d_out, off, idxarr, hmax, flagp);
    pfn1p_kernel<<<(MPIL + 3) / 4, 256, 0, stream>>>(d_out, hmax, d_in[8], d_in[9],
                                                     off, idxarr, unq, occ8, flagp);

    dilate1_kernel<<<(BATCH * GRID0 * GRID0) / 256, 256, 0, stream>>>(occ8, occ1m);
    dilate2_kernel<<<(BATCH * 128 * 128) / 256, 256, 0, stream>>>(occ1m, occ2m);

    dim3 blk(256);
    // block 1 (64ch, stride 1): R=8, WC=1/WP=4 (CG=4, RPW=2), 1024 blocks
    dim3 g1(16, 32, BATCH);
    convmf_kernel<64, 64, 1, 8, 2, 1, false><<<g1, blk, 0, stream>>>(
        d_out, 0, 1, nullptr, 0, FB1, d_in[11], d_in[12], occ1m, flagp, 256, 256, 256, 256);
    convmf_kernel<64, 64, 1, 8, 2, 1, false><<<g1, blk, 0, stream>>>(
        d_out, 1, 2, nullptr, 0, FB2, d_in[14], d_in[15], occ1m, flagp, 256, 256, 256, 256);
    convmf_kernel<64, 64, 1, 8, 2, 1, true><<<g1, blk, 0, stream>>>(
        d_out, 2, 0, nullptr, 1, FB3, d_in[17], d_in[18], occ1m, flagp, 256, 256, 256, 256);
    // block 2: stride-2 (R=4) and 128ch (R=4), COUT-split x2, WC=1/WP=4 (CG=4, RPW=1)
    dim3 g2a(8, 32, BATCH * 2), g2b(8, 32, BATCH * 2);
    convmf_kernel<64, 128, 2, 4, 1, 2, false><<<g2a, blk, 0, stream>>>(
        d_out, 0, 1, nullptr, 0, FB4, d_in[20], d_in[21], occ2m, flagp, 256, 256, 128, 128);
    convmf_kernel<128, 128, 1, 4, 1, 2, false><<<g2b, blk, 0, stream>>>(
        d_out, 1, 2, nullptr, 0, FB5, d_in[23], d_in[24], occ2m, flagp, 128, 128, 128, 128);
    convmf_kernel<128, 128, 1, 4, 1, 2, true><<<g2b, blk, 0, stream>>>(
        d_out, 2, 0, Fx, 1, FB6, d_in[26], d_in[27], occ2m, flagp, 128, 128, 128, 128);

    // gather reads Fx (ws) + flag (ws), overwrites all of d_out
    gather_kernel<<<(NPTS * 32) / 256, 256, 0, stream>>>(Fx, d_in[0], unq, unq_inv,
                                                         d_out, flagp);
}